// Round 10
// baseline (1819.067 us; speedup 1.0000x reference)
//
#include <hip/hip_runtime.h>
#include <stdint.h>

#define NN 50000
#define NE 1600000

typedef _Float16 f16;
typedef __attribute__((ext_vector_type(8))) _Float16 h8;
typedef __attribute__((ext_vector_type(4))) _Float16 h4v;
typedef __attribute__((ext_vector_type(4))) float f32x4;
typedef __attribute__((ext_vector_type(2))) float f32x2;

union PackU { unsigned int u; f16 h[2]; };
union Pack4 { uint2 v; f16 h[4]; };
union Pack8 { uint4 v; f16 h[8]; };

__device__ __forceinline__ void storev(float* p, float v) { *p = v; }
__device__ __forceinline__ void storev(f16* p, float v) { *p = (f16)v; }

__device__ __forceinline__ unsigned char f2fp8(float v) {
    int pk = __builtin_amdgcn_cvt_pk_fp8_f32(v, v, 0, false);
    return (unsigned char)(pk & 0xff);
}

// Async global->LDS, 16 B per lane. HW semantics: LDS dest = wave-uniform
// base + lane*16; global src is PER-LANE. (learn_hip m97/m104/m173.)
__device__ __forceinline__ void gload_lds16(const f16* g, f16* l) {
    __builtin_amdgcn_global_load_lds(
        (const __attribute__((address_space(1))) void*)g,
        (__attribute__((address_space(3))) void*)l, 16, 0, 0);
}

// ---------------------------------------------------------------------------
// Preprocessing
// ---------------------------------------------------------------------------
__global__ __launch_bounds__(256) void zero_int_kernel(int* __restrict__ p, int n) {
    int i = blockIdx.x * 256 + threadIdx.x;
    if (i < n) p[i] = 0;
}

__global__ __launch_bounds__(256) void count_kernel(const int* __restrict__ dst,
                                                    int* __restrict__ deg, int nE) {
    int e = blockIdx.x * 256 + threadIdx.x;
    if (e < nE) atomicAdd(&deg[dst[e]], 1);
}

__global__ __launch_bounds__(256) void dinv_kernel(const int* __restrict__ deg,
                                                   float* __restrict__ dinv, int n) {
    int i = blockIdx.x * 256 + threadIdx.x;
    if (i < n) dinv[i] = rsqrtf((float)deg[i] + 1.0f);
}

// Parallel 3-phase exclusive scan over 50000 ints (196 blocks of 256).
__global__ __launch_bounds__(256) void scan1_kernel(const int* __restrict__ cnt,
                                                    int* __restrict__ rs,
                                                    int* __restrict__ bsum, int n) {
    __shared__ int sm[256];
    int b = blockIdx.x, t = threadIdx.x, i = b * 256 + t;
    int v = (i < n) ? cnt[i] : 0;
    sm[t] = v;
    __syncthreads();
    for (int off = 1; off < 256; off <<= 1) {
        int x = 0;
        if (t >= off) x = sm[t - off];
        __syncthreads();
        if (t >= off) sm[t] += x;
        __syncthreads();
    }
    if (i < n) rs[i] = sm[t] - v;  // block-local exclusive
    if (t == 255) bsum[b] = sm[255];
}

__global__ __launch_bounds__(256) void scan2_kernel(int* __restrict__ bsum,
                                                    int* __restrict__ rs, int nb, int n) {
    __shared__ int sm[256];
    int t = threadIdx.x;
    int v = (t < nb) ? bsum[t] : 0;
    sm[t] = v;
    __syncthreads();
    for (int off = 1; off < 256; off <<= 1) {
        int x = 0;
        if (t >= off) x = sm[t - off];
        __syncthreads();
        if (t >= off) sm[t] += x;
        __syncthreads();
    }
    if (t < nb) bsum[t] = sm[t] - v;  // exclusive block offsets
    if (t == 255) rs[n] = sm[255];    // grand total (= nE)
}

__global__ __launch_bounds__(256) void scan3_kernel(int* __restrict__ rs,
                                                    const int* __restrict__ bsum, int n) {
    int i = blockIdx.x * 256 + threadIdx.x;
    if (i < n) rs[i] += bsum[blockIdx.x];
}

__global__ __launch_bounds__(256) void fill_kernel(const int* __restrict__ src,
                                                   const int* __restrict__ dst,
                                                   const int* __restrict__ rs,
                                                   int* __restrict__ cur,
                                                   int* __restrict__ csr, int nE) {
    int e = blockIdx.x * 256 + threadIdx.x;
    if (e < nE) {
        int d = dst[e];
        int p = rs[d] + atomicAdd(&cur[d], 1);
        csr[p] = src[e];
    }
}

// w1p[k*4 + {0,1,2,3}] = {W1[0][k], W1[1][k], W1[2][k], b1[k]}
__global__ __launch_bounds__(256) void pack_w1_kernel(const float* __restrict__ W1,
                                                      const float* __restrict__ b1,
                                                      float* __restrict__ w1p) {
    int k = blockIdx.x * 256 + threadIdx.x;
    if (k < 4096) {
        w1p[k * 4 + 0] = W1[k];
        w1p[k * 4 + 1] = W1[4096 + k];
        w1p[k * 4 + 2] = W1[8192 + k];
        w1p[k * 4 + 3] = b1[k];
    }
}

// Transpose-convert: Wt[n][k] = f16(W[k][n]); K, N multiples of 32.
__global__ __launch_bounds__(256) void tconv_kernel(const float* __restrict__ W,
                                                    f16* __restrict__ Wt,
                                                    int K, int N) {
    __shared__ float tile[32][33];
    int kb = blockIdx.y * 32, nb = blockIdx.x * 32;
    int tx = threadIdx.x & 31, ty = threadIdx.x >> 5;
    for (int r = ty; r < 32; r += 8)
        tile[r][tx] = W[(size_t)(kb + r) * N + nb + tx];
    __syncthreads();
    for (int r = ty; r < 32; r += 8)
        Wt[(size_t)(nb + r) * K + kb + tx] = (f16)tile[tx][r];
}

// ---------------------------------------------------------------------------
// fp32-input aggregation (widths 3, 64, 16)
// ---------------------------------------------------------------------------
template <int F, int TPN, bool RELU, bool BIAS, typename OutT>
__global__ __launch_bounds__(256) void agg_kernel(const float* __restrict__ t,
                                                  const float* __restrict__ dinv,
                                                  const int* __restrict__ rs,
                                                  const int* __restrict__ csr,
                                                  const float* __restrict__ bias,
                                                  OutT* __restrict__ out, int out_ld,
                                                  int nNodes) {
    constexpr int NPB = 256 / TPN;
    constexpr int C   = F / TPN;
    static_assert(TPN * C == F, "F must be TPN*C");
    int node = blockIdx.x * NPB + (int)threadIdx.x / TPN;
    if (node >= nNodes) return;
    int lane = (int)threadIdx.x % TPN;

    float acc[C];
#pragma unroll
    for (int c = 0; c < C; ++c) acc[c] = 0.f;

    int e0 = rs[node], e1 = rs[node + 1];
    for (int e = e0; e < e1; ++e) {
        int s = csr[e];
        float w = dinv[s];
        const float* tr = t + (size_t)s * F;
#pragma unroll
        for (int c = 0; c < C; ++c) acc[c] += w * tr[lane + c * TPN];
    }
    float di = dinv[node];
    const float* ti = t + (size_t)node * F;
    OutT* oi = out + (size_t)node * out_ld;
#pragma unroll
    for (int c = 0; c < C; ++c) {
        int col = lane + c * TPN;
        float v = di * acc[c] + di * di * ti[col];
        if (BIAS) v += bias[col];
        if (RELU) v = fmaxf(v, 0.f);
        storev(oi + col, v);
    }
}

// ---------------------------------------------------------------------------
// fp8 aggregation, F=1024, SINGLE PASS: 64 lanes/node (4 nodes/block), each
// lane loads a uint4 (16 B = 16 fp8 cols) per edge -> one VMEM instruction
// covers the whole 1 KB row per wave.
// ---------------------------------------------------------------------------
template <bool RELU>
__global__ __launch_bounds__(256) void agg_fp8_1024(const unsigned char* __restrict__ t,
                                                    const float* __restrict__ dinv,
                                                    const int* __restrict__ rs,
                                                    const int* __restrict__ csr,
                                                    const float* __restrict__ bias,
                                                    f16* __restrict__ out, int nNodes) {
    int node = blockIdx.x * 4 + ((int)threadIdx.x >> 6);
    if (node >= nNodes) return;
    int lane = (int)threadIdx.x & 63;

    float acc[16];
#pragma unroll
    for (int j = 0; j < 16; ++j) acc[j] = 0.f;

    int e0 = rs[node], e1 = rs[node + 1];
    int e = e0;
    for (; e + 1 < e1; e += 2) {
        int s0 = csr[e], s1 = csr[e + 1];
        float w0 = dinv[s0], w1 = dinv[s1];
        uint4 u0 = ((const uint4*)(t + (size_t)s0 * 1024))[lane];
        uint4 u1 = ((const uint4*)(t + (size_t)s1 * 1024))[lane];
        const unsigned int uw0[4] = {u0.x, u0.y, u0.z, u0.w};
        const unsigned int uw1[4] = {u1.x, u1.y, u1.z, u1.w};
#pragma unroll
        for (int q = 0; q < 4; ++q) {
            f32x2 l0 = __builtin_amdgcn_cvt_pk_f32_fp8((int)uw0[q], false);
            f32x2 h0 = __builtin_amdgcn_cvt_pk_f32_fp8((int)uw0[q], true);
            f32x2 l1 = __builtin_amdgcn_cvt_pk_f32_fp8((int)uw1[q], false);
            f32x2 h1 = __builtin_amdgcn_cvt_pk_f32_fp8((int)uw1[q], true);
            acc[q * 4 + 0] += w0 * l0.x + w1 * l1.x;
            acc[q * 4 + 1] += w0 * l0.y + w1 * l1.y;
            acc[q * 4 + 2] += w0 * h0.x + w1 * h1.x;
            acc[q * 4 + 3] += w0 * h0.y + w1 * h1.y;
        }
    }
    if (e < e1) {
        int s0 = csr[e];
        float w0 = dinv[s0];
        uint4 u0 = ((const uint4*)(t + (size_t)s0 * 1024))[lane];
        const unsigned int uw0[4] = {u0.x, u0.y, u0.z, u0.w};
#pragma unroll
        for (int q = 0; q < 4; ++q) {
            f32x2 l0 = __builtin_amdgcn_cvt_pk_f32_fp8((int)uw0[q], false);
            f32x2 h0 = __builtin_amdgcn_cvt_pk_f32_fp8((int)uw0[q], true);
            acc[q * 4 + 0] += w0 * l0.x;
            acc[q * 4 + 1] += w0 * l0.y;
            acc[q * 4 + 2] += w0 * h0.x;
            acc[q * 4 + 3] += w0 * h0.y;
        }
    }
    float di = dinv[node], di2 = di * di;
    uint4 us = ((const uint4*)(t + (size_t)node * 1024))[lane];
    const unsigned int uws[4] = {us.x, us.y, us.z, us.w};
    Pack8 o0, o1;
#pragma unroll
    for (int q = 0; q < 4; ++q) {
        f32x2 sl = __builtin_amdgcn_cvt_pk_f32_fp8((int)uws[q], false);
        f32x2 sh = __builtin_amdgcn_cvt_pk_f32_fp8((int)uws[q], true);
        float4 b = *(const float4*)(bias + 16 * lane + q * 4);
        float v0 = di * acc[q * 4 + 0] + di2 * sl.x + b.x;
        float v1 = di * acc[q * 4 + 1] + di2 * sl.y + b.y;
        float v2 = di * acc[q * 4 + 2] + di2 * sh.x + b.z;
        float v3 = di * acc[q * 4 + 3] + di2 * sh.y + b.w;
        if (RELU) {
            v0 = fmaxf(v0, 0.f); v1 = fmaxf(v1, 0.f);
            v2 = fmaxf(v2, 0.f); v3 = fmaxf(v3, 0.f);
        }
        Pack8& dst8 = (q < 2) ? o0 : o1;
        int base = (q & 1) * 4;
        dst8.h[base + 0] = (f16)v0;
        dst8.h[base + 1] = (f16)v1;
        dst8.h[base + 2] = (f16)v2;
        dst8.h[base + 3] = (f16)v3;
    }
    uint4* orow = (uint4*)(out + (size_t)node * 1024 + 16 * lane);
    orow[0] = o0.v;
    orow[1] = o1.v;
}

// ---------------------------------------------------------------------------
// fp8 aggregation over a 256-col tensor (layer 3): 64 lanes/node, one uint
// (4 fp8 cols) per lane per edge. Round-8-proven structure.
// ---------------------------------------------------------------------------
template <bool RELU>
__global__ __launch_bounds__(256) void agg_fp8_256(const unsigned char* __restrict__ t,
                                                   int in_ld,
                                                   const float* __restrict__ dinv,
                                                   const int* __restrict__ rs,
                                                   const int* __restrict__ csr,
                                                   const float* __restrict__ bias,
                                                   f16* __restrict__ out,
                                                   int out_ld, int nNodes) {
    int node = blockIdx.x * 4 + ((int)threadIdx.x >> 6);
    if (node >= nNodes) return;
    int lane = (int)threadIdx.x & 63;

    float acc0 = 0.f, acc1 = 0.f, acc2 = 0.f, acc3 = 0.f;
    int e0 = rs[node], e1 = rs[node + 1];
    int e = e0;
    for (; e + 1 < e1; e += 2) {
        int s0 = csr[e], s1 = csr[e + 1];
        float w0 = dinv[s0], w1 = dinv[s1];
        unsigned int u0 = ((const unsigned int*)(t + (size_t)s0 * in_ld))[lane];
        unsigned int u1 = ((const unsigned int*)(t + (size_t)s1 * in_ld))[lane];
        f32x2 l0 = __builtin_amdgcn_cvt_pk_f32_fp8((int)u0, false);
        f32x2 h0 = __builtin_amdgcn_cvt_pk_f32_fp8((int)u0, true);
        f32x2 l1 = __builtin_amdgcn_cvt_pk_f32_fp8((int)u1, false);
        f32x2 h1 = __builtin_amdgcn_cvt_pk_f32_fp8((int)u1, true);
        acc0 += w0 * l0.x + w1 * l1.x;
        acc1 += w0 * l0.y + w1 * l1.y;
        acc2 += w0 * h0.x + w1 * h1.x;
        acc3 += w0 * h0.y + w1 * h1.y;
    }
    if (e < e1) {
        int s0 = csr[e];
        float w0 = dinv[s0];
        unsigned int u0 = ((const unsigned int*)(t + (size_t)s0 * in_ld))[lane];
        f32x2 l0 = __builtin_amdgcn_cvt_pk_f32_fp8((int)u0, false);
        f32x2 h0 = __builtin_amdgcn_cvt_pk_f32_fp8((int)u0, true);
        acc0 += w0 * l0.x;
        acc1 += w0 * l0.y;
        acc2 += w0 * h0.x;
        acc3 += w0 * h0.y;
    }
    float di = dinv[node], di2 = di * di;
    unsigned int us = ((const unsigned int*)(t + (size_t)node * in_ld))[lane];
    f32x2 sl = __builtin_amdgcn_cvt_pk_f32_fp8((int)us, false);
    f32x2 sh = __builtin_amdgcn_cvt_pk_f32_fp8((int)us, true);
    float4 b = *(const float4*)(bias + 4 * lane);
    float v0 = di * acc0 + di2 * sl.x + b.x;
    float v1 = di * acc1 + di2 * sl.y + b.y;
    float v2 = di * acc2 + di2 * sh.x + b.z;
    float v3 = di * acc3 + di2 * sh.y + b.w;
    if (RELU) {
        v0 = fmaxf(v0, 0.f); v1 = fmaxf(v1, 0.f);
        v2 = fmaxf(v2, 0.f); v3 = fmaxf(v3, 0.f);
    }
    Pack4 pk;
    pk.h[0] = (f16)v0; pk.h[1] = (f16)v1; pk.h[2] = (f16)v2; pk.h[3] = (f16)v3;
    *(uint2*)(out + (size_t)node * out_ld + 4 * lane) = pk.v;
}

// ---------------------------------------------------------------------------
// MFMA GEMM kernels. LDS row stride 40 f16 = 80 B (16 B-aligned).
// Fragments: A[m=lane&15][k=(lane>>4)*8+j]; B^T rows; C/D col=lane&15,
// row=(lane>>4)*4+reg.
// ---------------------------------------------------------------------------
#define LDSTR 40

// Fused layer1+2, round-24 (mfma12): mfma10 (735 us, best) with B staging
// via __builtin_amdgcn_global_load_lds (width 16):
//  * B LDS layout = mfma11's fragment-order (proven bit-correct in r9):
//    subtile t at Bs + t*512 f16; slot lane*16B = row (lane&15)+16t,
//    k-chunk (lane>>4). This is EXACTLY global_load_lds's HW write pattern
//    (wave-uniform base + lane*16, per-lane global src).
//  * Removes per K-step per thread: 2 global loads into VGPR + 2
//    ds_write_b128 + the pb register chain (~8 VGPR freed). DMA is issued
//    right after the barrier -> drains under A-VALU + frag reads + MFMA
//    (~700+ cyc >> L2 latency) before the next barrier's implicit vmcnt(0).
//  * r9 lesson: bank conflicts are OFF the critical path in this 2-phase
//    schedule (3rd falsification) — mfma11's regression is attributed to
//    the staging round-trip, which this removes. A path byte-identical to
//    mfma10 (LDSTR-40). LDS 52.5 KB, 2 blocks/CU (VGPR-capped).
// Pre-committed: >= 745 us -> revert to mfma10, gemm12 declared at its
// structure ceiling, pivot to tail kernels.
__global__ __launch_bounds__(512, 4) void gemm12_mfma12(const float* __restrict__ aggx,
                                                        const float* __restrict__ w1p,
                                                        const f16* __restrict__ Bt,
                                                        unsigned char* __restrict__ t2) {
    __shared__ f16 As[2 * 128 * LDSTR] __attribute__((aligned(16)));   // 20.5 KB
    __shared__ f16 Bs[2 * 16 * 512] __attribute__((aligned(16)));      // 32 KB
    int tid = threadIdx.x;
    int m0  = blockIdx.x * 128;
    int n0c = blockIdx.y * 256;  // column chunk base in W2

    // A-recompute: 2 m-rows x 4 k per thread (64 row-pairs x 8 k-groups)
    int mg = tid >> 3;   // 0..63 -> rows 2mg, 2mg+1
    int kg = tid & 7;    // k group: kg*4 .. kg*4+3
    float a0[2], a1[2], a2[2];
#pragma unroll
    for (int j = 0; j < 2; ++j) {
        int gm = m0 + mg * 2 + j;
        if (gm < NN) {
            a0[j] = aggx[gm * 3 + 0];
            a1[j] = aggx[gm * 3 + 1];
            a2[j] = aggx[gm * 3 + 2];
        } else {
            a0[j] = a1[j] = a2[j] = 0.f;
        }
    }

    int lane   = tid & 63;
    int wv     = tid >> 6;          // 0..7
    int wm     = (wv >> 2) * 64;    // 0 or 64
    int wn     = (wv & 3) * 64;     // 0,64,128,192
    int fr_m   = lane & 15;
    int khalf8 = (lane >> 4) * 8;
    int sb     = (wv & 3) * 4;      // B subtile base for this wave's wn

    // B staging via global_load_lds: wave wv stages subtiles 2wv, 2wv+1.
    // Per-lane global src: row (lane&15)+16t, k-chunk (lane>>4). LDS dest
    // is the wave-uniform subtile base; HW appends lane*16 B.
    const f16* gB0 = Bt + (size_t)(n0c + (2 * wv)     * 16 + fr_m) * 4096 + khalf8;
    const f16* gB1 = Bt + (size_t)(n0c + (2 * wv + 1) * 16 + fr_m) * 4096 + khalf8;
    int bsub0 = (2 * wv)     * 512;   // f16 units (uniform per wave)
    int bsub1 = (2 * wv + 1) * 512;

    // A-stage helper (r0 body, parameterized destination buffer + k)
    auto stageA = [&](f16* dstAs, int kk) {
        int kb = kk + kg * 4;
        float4 wk0 = *(const float4*)(w1p + (size_t)(kb + 0) * 4);
        float4 wk1 = *(const float4*)(w1p + (size_t)(kb + 1) * 4);
        float4 wk2 = *(const float4*)(w1p + (size_t)(kb + 2) * 4);
        float4 wk3 = *(const float4*)(w1p + (size_t)(kb + 3) * 4);
#pragma unroll
        for (int j = 0; j < 2; ++j) {
            float h0 = fmaxf(a0[j] * wk0.x + a1[j] * wk0.y + a2[j] * wk0.z + wk0.w, 0.f);
            float h1 = fmaxf(a0[j] * wk1.x + a1[j] * wk1.y + a2[j] * wk1.z + wk1.w, 0.f);
            float h2 = fmaxf(a0[j] * wk2.x + a1[j] * wk2.y + a2[j] * wk2.z + wk2.w, 0.f);
            float h3 = fmaxf(a0[j] * wk3.x + a1[j] * wk3.y + a2[j] * wk3.z + wk3.w, 0.f);
            Pack4 pk;
            pk.h[0] = (f16)h0; pk.h[1] = (f16)h1; pk.h[2] = (f16)h2; pk.h[3] = (f16)h3;
            *(uint2*)(&dstAs[(mg * 2 + j) * LDSTR + kg * 4]) = pk.v;
        }
    };

    // ---- prologue: stage buffer 0 with k=0 (B via DMA, A via VALU) ----
    gload_lds16(gB0, &Bs[bsub0]);
    gload_lds16(gB1, &Bs[bsub1]);
    stageA(As, 0);

    f32x4 acc[4][4];
#pragma unroll
    for (int i = 0; i < 4; ++i)
#pragma unroll
        for (int j = 0; j < 4; ++j) acc[i][j] = (f32x4){0.f, 0.f, 0.f, 0.f};

    int p = 0;
    for (int k0 = 0; k0 < 4096; k0 += 32) {
        __syncthreads();  // drains DMA for buf[p]; all reads of buf[p^1] done
        const f16* Asc = As + p * (128 * LDSTR);
        const f16* Bsc = Bs + p * (16 * 512);
        f16* Asn = As + (p ^ 1) * (128 * LDSTR);
        f16* Bsn = Bs + (p ^ 1) * (16 * 512);

        // ---- issue next B DMA FIRST (drains across the whole K-step) ----
        int k1 = k0 + 32;
        if (k1 < 4096) {
            gload_lds16(gB0 + k1, &Bsn[bsub0]);
            gload_lds16(gB1 + k1, &Bsn[bsub1]);
            // ---- A-stage for next tile (VALU, overlaps others' MFMA) ----
            stageA(Asn, k1);
        }

        // ---- frag reads from current buffer ----
        h8 af[4];
#pragma unroll
        for (int mt = 0; mt < 4; ++mt)
            af[mt] = *(const h8*)(&Asc[(wm + mt * 16 + fr_m) * LDSTR + khalf8]);

#pragma unroll
        for (int nt = 0; nt < 4; ++nt) {
            h8 bf = *(const h8*)(&Bsc[(sb + nt) * 512 + lane * 8]);
#pragma unroll
            for (int mt = 0; mt < 4; ++mt)
                acc[mt][nt] = __builtin_amdgcn_mfma_f32_16x16x32_f16(af[mt], bf, acc[mt][nt], 0, 0, 0);
        }
        p ^= 1;
    }

#pragma unroll
    for (int mt = 0; mt < 4; ++mt) {
#pragma unroll
        for (int reg = 0; reg < 4; ++reg) {
            int gm = m0 + wm + mt * 16 + (lane >> 4) * 4 + reg;
            if (gm < NN) {
                unsigned char* orow = t2 + (size_t)gm * 1024 + n0c + wn + fr_m;
#pragma unroll
                for (int nt = 0; nt < 4; ++nt)
                    orow[nt * 16] = f2fp8(acc[mt][nt][reg]);
            }
        }
    }
}

// Generic MFMA GEMM (layer 3): C(fp8)[M,ldc] = A[M,lda](f16) @ Bt[N][K](f16)^T
// 128x128 tile, register-prefetched staging. 20.5 KB LDS -> 8 blocks/CU.
__global__ __launch_bounds__(256) void gemm_mfma(const f16* __restrict__ A, int lda,
                                                 const f16* __restrict__ Bt, int K,
                                                 unsigned char* __restrict__ C, int ldc,
                                                 int M) {
    __shared__ f16 As[128 * LDSTR] __attribute__((aligned(16)));
    __shared__ f16 Bs[128 * LDSTR] __attribute__((aligned(16)));
    int tid = threadIdx.x;
    int m0 = blockIdx.y * 128;
    int n0 = blockIdx.x * 128;

    int row = tid >> 1;
    int kof = (tid & 1) * 16;
    int am  = m0 + row;
    if (am > M - 1) am = M - 1;

    int lane   = tid & 63;
    int wv     = tid >> 6;
    int fr_m   = lane & 15;
    int khalf8 = (lane >> 4) * 8;

    const f16* abase = A + (size_t)am * lda + kof;
    const f16* bbase = Bt + (size_t)(n0 + row) * K + kof;

    h8 pa0 = *(const h8*)(abase);
    h8 pa1 = *(const h8*)(abase + 8);
    h8 pb0 = *(const h8*)(bbase);
    h8 pb1 = *(const h8*)(bbase + 8);

    f32x4 acc[2][8];
#pragma unroll
    for (int i = 0; i < 2; ++i)
#pragma unroll
        for (int j = 0; j < 8; ++j) acc[i][j] = (f32x4){0.f, 0.f, 0.f, 0.f};

    for (int k0 = 0; k0 < K; k0 += 32) {
        *(h8*)(&As[row * LDSTR + kof]) = pa0;
        *(h8*)(&As[row * LDSTR + kof + 8]) = pa1;
        *(h8*)(&Bs[row * LDSTR + kof]) = pb0;
        *(h8*)(&Bs[row * LDSTR + kof + 8]) = pb1;
        __syncthreads();

        int kn = k0 + 32;
        if (kn < K) {
            pa0 = *(const h8*)(abase + kn);
            pa1 = *(const h8*)(abase + kn + 8);
            pb0 = *(const h8*)(bbase + kn);
            pb1 = *(const h8*)(bbase + kn + 8);
        }

        h8 af0 = *(const h8*)(&As[(wv * 32 + fr_m) * LDSTR + khalf8]);
        h8 af1 = *(const h8*)(&As[(wv * 32 + 16 + fr_m) * LDSTR + khalf8]);
#pragma unroll
        for (int nt = 0; nt < 8; ++nt) {
            h8 bf = *(const h8*)(&Bs[(nt * 16 + fr_m) * LDSTR + khalf8]);
            acc[0][nt] = __builtin_amdgcn_mfma_f32_16x16x32_f16(af0, bf, acc[0][nt], 0, 0, 0);
            acc[1][nt] = __builtin_amdgcn_mfma_f32_16x16x32_f16(af1, bf, acc[1][nt], 0, 0, 0);
        }
        __syncthreads();
    }

#pragma unroll
    for (int mt = 0; mt < 2; ++mt) {
#pragma unroll
        for (int reg = 0; reg < 4; ++reg) {
            int gm = m0 + wv * 32 + mt * 16 + (lane >> 4) * 4 + reg;
            if (gm < M) {
                unsigned char* orow = C + (size_t)gm * ldc + n0 + fr_m;
#pragma unroll
                for (int nt = 0; nt < 8; ++nt)
                    orow[nt * 16] = f2fp8(acc[mt][nt][reg]);
            }
        }
    }
}

// ---------------------------------------------------------------------------
// Layer-4 GEMM: C[M,64] f32 = A[M,256](f16) @ B[256,64](f32)
// ---------------------------------------------------------------------------
#define BM 64
#define BN 64
#define BKS 16
__global__ __launch_bounds__(256) void gemm_f16A_kernel(const f16* __restrict__ A,
                                                        const float* __restrict__ B,
                                                        float* __restrict__ C,
                                                        int M, int K, int N) {
    __shared__ float As[BKS][BM + 4];
    __shared__ float Bs[BKS][BN + 4];
    int tid = threadIdx.x;
    int tx = tid & 15;
    int ty = tid >> 4;
    int m0 = blockIdx.y * BM;
    int n0 = blockIdx.x * BN;

    float acc[4][4];
#pragma unroll
    for (int i = 0; i < 4; ++i)
#pragma unroll
        for (int j = 0; j < 4; ++j) acc[i][j] = 0.f;

    int lmA = tid >> 2;
    int lkA = (tid & 3) * 4;
    int lkB = tid >> 4;
    int lnB = (tid & 15) * 4;

    for (int k0 = 0; k0 < K; k0 += BKS) {
        int gm = m0 + lmA;
        if (gm > M - 1) gm = M - 1;
        h4v av = *(const h4v*)(A + (size_t)gm * K + k0 + lkA);
        As[lkA + 0][lmA] = (float)av.x;
        As[lkA + 1][lmA] = (float)av.y;
        As[lkA + 2][lmA] = (float)av.z;
        As[lkA + 3][lmA] = (float)av.w;
        float4 bv = *reinterpret_cast<const float4*>(B + (size_t)(k0 + lkB) * N + n0 + lnB);
        *reinterpret_cast<float4*>(&Bs[lkB][lnB]) = bv;
        __syncthreads();

#pragma unroll
        for (int k = 0; k < BKS; ++k) {
            float4 a4 = *reinterpret_cast<const float4*>(&As[k][ty * 4]);
            float4 b4 = *reinterpret_cast<const float4*>(&Bs[k][tx * 4]);
            float a[4] = {a4.x, a4.y, a4.z, a4.w};
            float b[4] = {b4.x, b4.y, b4.z, b4.w};
#pragma unroll
            for (int i = 0; i < 4; ++i)
#pragma unroll
                for (int j = 0; j < 4; ++j) acc[i][j] += a[i] * b[j];
        }
        __syncthreads();
    }

#pragma unroll
    for (int i = 0; i < 4; ++i) {
        int m = m0 + ty * 4 + i;
        if (m < M) {
            float4 o = make_float4(acc[i][0], acc[i][1], acc[i][2], acc[i][3]);
            *reinterpret_cast<float4*>(C + (size_t)m * N + n0 + tx * 4) = o;
        }
    }
}

// Layer-5 GEMM: t5 = h4[NN,64](f16) @ W5[64,16](f32)
__global__ __launch_bounds__(256) void gemm5_kernel(const f16* __restrict__ h4,
                                                    const float* __restrict__ W5,
                                                    float* __restrict__ t5, int nNodes) {
    int idx = blockIdx.x * 256 + threadIdx.x;
    int i = idx >> 4, j = idx & 15;
    if (i >= nNodes) return;
    const f16* a = h4 + (size_t)i * 64;
    float s = 0.f;
#pragma unroll
    for (int k = 0; k < 64; ++k) s += (float)a[k] * W5[k * 16 + j];
    t5[idx] = s;
}

// Pool + classifier
__global__ __launch_bounds__(256) void pool_kernel(const float* __restrict__ h5,
                                                   float* __restrict__ pool) {
    __shared__ float red[256];
    int c = blockIdx.x;
    float s = 0.f;
    for (int i = threadIdx.x; i < NN; i += 256) s += h5[(size_t)i * 16 + c];
    red[threadIdx.x] = s;
    __syncthreads();
    for (int off = 128; off > 0; off >>= 1) {
        if ((int)threadIdx.x < off) red[threadIdx.x] += red[threadIdx.x + off];
        __syncthreads();
    }
    if (threadIdx.x == 0) pool[c] = red[0];
}

__global__ void final_kernel(const float* __restrict__ pool, const float* __restrict__ Wl,
                             const float* __restrict__ bl, float* __restrict__ out) {
    int j = threadIdx.x;
    if (j < 3) {
        float s = 0.f;
#pragma unroll
        for (int c = 0; c < 16; ++c) s += pool[c] * Wl[c * 3 + j];
        out[j] = s * (1.0f / (float)NN) + bl[j];
    }
}

// ---------------------------------------------------------------------------
// Host launcher — workspace ledger identical to rounds 7-13 (~205 MB, proven).
// ---------------------------------------------------------------------------
extern "C" void kernel_launch(void* const* d_in, const int* in_sizes, int n_in,
                              void* d_out, int out_size, void* d_ws, size_t ws_size,
                              hipStream_t stream) {
    (void)in_sizes; (void)n_in; (void)out_size; (void)ws_size;

    const float* x  = (const float*)d_in[0];
    const int*   ei = (const int*)d_in[1];
    const float* W1 = (const float*)d_in[2];
    const float* b1 = (const float*)d_in[3];
    const float* W2 = (const float*)d_in[4];
    const float* b2 = (const float*)d_in[5];
    const float* W3 = (const float*)d_in[6];
    const float* b3 = (const float*)d_in[7];
    const float* W4 = (const float*)d_in[8];
    const float* b4 = (const float*)d_in[9];
    const float* W5 = (const float*)d_in[10];
    const float* b5 = (const float*)d_in[11];
    const float* Wl = (const float*)d_in[12];
    const float* bl = (const float*)d_in[13];
    float* out = (float*)d_out;

    const int* srcp = ei;
    const int* dstp = ei + NE;

    char* p = (char*)d_ws;
    auto carve = [&](size_t bytes) {
        char* r = p;
        p += (bytes + 255) & ~(size_t)255;
        return r;
    };
    int*   deg  = (int*)carve(NN * 4);
    int*   cur  = (int*)carve(NN * 4);
    int*   rs   = (int*)carve((NN + 1) * 4);
    int*   bsum = (int*)carve(256 * 4);
    int*   csr  = (int*)carve((size_t)NE * 4);
    float* dinv = (float*)carve(NN * 4);
    float* aggx = (float*)carve((size_t)NN * 3 * 4);
    float* pool = (float*)carve(16 * 4);
    float* w1p  = (float*)carve((size_t)4096 * 4 * 4);       // 64 KB
    f16*   w2t  = (f16*)carve((size_t)1024 * 4096 * 2);      // 8.4 MB
    f16*   w3t  = (f16*)carve((size_t)256 * 1024 * 2);       // 0.5 MB
    unsigned char* tbuf = (unsigned char*)carve((size_t)NN * 1024);  // 51.2 MB: fp8 t2[NN,1024] / t3 / f32 t4,t5 view
    f16*   h2   = (f16*)carve((size_t)NN * 1024 * 2);        // 102.4 MB
    f16*   h3   = (f16*)carve((size_t)NN * 256 * 2);         // 25.6 MB
    f16*   h4   = (f16*)carve((size_t)NN * 64 * 2);          // 6.4 MB
    float* h5   = (float*)carve((size_t)NN * 16 * 4);        // 3.2 MB
    float* tf32 = (float*)tbuf;                              // f32 view for t4/t5

    const int NB = (NN + 255) / 256;  // 196

    zero_int_kernel<<<NB, 256, 0, stream>>>(deg, NN);
    zero_int_kernel<<<NB, 256, 0, stream>>>(cur, NN);
    count_kernel<<<(NE + 255) / 256, 256, 0, stream>>>(dstp, deg, NE);
    dinv_kernel<<<NB, 256, 0, stream>>>(deg, dinv, NN);
    scan1_kernel<<<NB, 256, 0, stream>>>(deg, rs, bsum, NN);
    scan2_kernel<<<1, 256, 0, stream>>>(bsum, rs, NB, NN);
    scan3_kernel<<<NB, 256, 0, stream>>>(rs, bsum, NN);
    fill_kernel<<<(NE + 255) / 256, 256, 0, stream>>>(srcp, dstp, rs, cur, csr, NE);

    // Weight prep
    pack_w1_kernel<<<16, 256, 0, stream>>>(W1, b1, w1p);
    tconv_kernel<<<dim3(1024 / 32, 4096 / 32), 256, 0, stream>>>(W2, w2t, 4096, 1024);
    tconv_kernel<<<dim3(256 / 32, 1024 / 32), 256, 0, stream>>>(W3, w3t, 1024, 256);

    // aggx = A_hat @ x (width 3, fp32)
    agg_kernel<3, 1, false, false, float><<<NB, 256, 0, stream>>>(
        x, dinv, rs, csr, nullptr, aggx, 3, NN);

    const int MB2 = (NN + 127) / 128;  // 391

    // Layers 1+2 fused: one 512-thread MFMA launch for all 1024 cols (fp8 out)
    gemm12_mfma12<<<dim3(MB2, 4), 512, 0, stream>>>(aggx, w1p, w2t, tbuf);
    // h2 = relu(A_hat t2 + b2): ONE pass, uint4/lane (16 B) per edge
    agg_fp8_1024<true><<<(NN + 3) / 4, 256, 0, stream>>>(
        tbuf, dinv, rs, csr, b2, h2, NN);

    // Layer 3 (MFMA, fp8 out): t3 = h2 @ W3; h3 = relu(A_hat t3 + b3)
    gemm_mfma<<<dim3(2, MB2), 256, 0, stream>>>(
        h2, 1024, w3t, 1024, tbuf, 256, NN);
    agg_fp8_256<true><<<(NN + 3) / 4, 256, 0, stream>>>(
        tbuf, 256, dinv, rs, csr, b3, h3, 256, NN);

    // Layer 4: t4 = h3 @ W4 [NN,64] f32; h4 = relu(A_hat t4 + b4) -> f16
    gemm_f16A_kernel<<<dim3(1, (NN + BM - 1) / BM), 256, 0, stream>>>(
        h3, W4, tf32, NN, 256, 64);
    agg_kernel<64, 64, true, true, f16><<<(NN + 3) / 4, 256, 0, stream>>>(
        tf32, dinv, rs, csr, b4, h4, 64, NN);

    // Layer 5: t5 = h4 @ W5 [NN,16] f32; h5 = A_hat t5 + b5 (no relu)
    gemm5_kernel<<<(NN * 16 + 255) / 256, 256, 0, stream>>>(h4, W5, tf32, NN);
    agg_kernel<16, 16, false, true, float><<<(NN + 15) / 16, 256, 0, stream>>>(
        tf32, dinv, rs, csr, b5, h5, 16, NN);

    // Global mean pool + classifier
    pool_kernel<<<16, 256, 0, stream>>>(h5, pool);
    final_kernel<<<1, 64, 0, stream>>>(pool, Wl, bl, out);
}

// Round 11
// 1610.685 us; speedup vs baseline: 1.1294x; 1.1294x over previous
//
#include <hip/hip_runtime.h>
#include <stdint.h>

#define NN 50000
#define NE 1600000

typedef _Float16 f16;
typedef __attribute__((ext_vector_type(8))) _Float16 h8;
typedef __attribute__((ext_vector_type(4))) _Float16 h4v;
typedef __attribute__((ext_vector_type(4))) float f32x4;
typedef __attribute__((ext_vector_type(2))) float f32x2;

union PackU { unsigned int u; f16 h[2]; };
union Pack4 { uint2 v; f16 h[4]; };
union Pack8 { uint4 v; f16 h[8]; };

__device__ __forceinline__ void storev(float* p, float v) { *p = v; }
__device__ __forceinline__ void storev(f16* p, float v) { *p = (f16)v; }

__device__ __forceinline__ unsigned char f2fp8(float v) {
    int pk = __builtin_amdgcn_cvt_pk_fp8_f32(v, v, 0, false);
    return (unsigned char)(pk & 0xff);
}

// ---------------------------------------------------------------------------
// Preprocessing
// ---------------------------------------------------------------------------
__global__ __launch_bounds__(256) void zero_int_kernel(int* __restrict__ p, int n) {
    int i = blockIdx.x * 256 + threadIdx.x;
    if (i < n) p[i] = 0;
}

__global__ __launch_bounds__(256) void count_kernel(const int* __restrict__ dst,
                                                    int* __restrict__ deg, int nE) {
    int e = blockIdx.x * 256 + threadIdx.x;
    if (e < nE) atomicAdd(&deg[dst[e]], 1);
}

__global__ __launch_bounds__(256) void dinv_kernel(const int* __restrict__ deg,
                                                   float* __restrict__ dinv, int n) {
    int i = blockIdx.x * 256 + threadIdx.x;
    if (i < n) dinv[i] = rsqrtf((float)deg[i] + 1.0f);
}

// Parallel 3-phase exclusive scan over 50000 ints (196 blocks of 256).
__global__ __launch_bounds__(256) void scan1_kernel(const int* __restrict__ cnt,
                                                    int* __restrict__ rs,
                                                    int* __restrict__ bsum, int n) {
    __shared__ int sm[256];
    int b = blockIdx.x, t = threadIdx.x, i = b * 256 + t;
    int v = (i < n) ? cnt[i] : 0;
    sm[t] = v;
    __syncthreads();
    for (int off = 1; off < 256; off <<= 1) {
        int x = 0;
        if (t >= off) x = sm[t - off];
        __syncthreads();
        if (t >= off) sm[t] += x;
        __syncthreads();
    }
    if (i < n) rs[i] = sm[t] - v;  // block-local exclusive
    if (t == 255) bsum[b] = sm[255];
}

__global__ __launch_bounds__(256) void scan2_kernel(int* __restrict__ bsum,
                                                    int* __restrict__ rs, int nb, int n) {
    __shared__ int sm[256];
    int t = threadIdx.x;
    int v = (t < nb) ? bsum[t] : 0;
    sm[t] = v;
    __syncthreads();
    for (int off = 1; off < 256; off <<= 1) {
        int x = 0;
        if (t >= off) x = sm[t - off];
        __syncthreads();
        if (t >= off) sm[t] += x;
        __syncthreads();
    }
    if (t < nb) bsum[t] = sm[t] - v;  // exclusive block offsets
    if (t == 255) rs[n] = sm[255];    // grand total (= nE)
}

__global__ __launch_bounds__(256) void scan3_kernel(int* __restrict__ rs,
                                                    const int* __restrict__ bsum, int n) {
    int i = blockIdx.x * 256 + threadIdx.x;
    if (i < n) rs[i] += bsum[blockIdx.x];
}

// fill: csr2[p] = {src, bits(dinv[src])} — fuses the edge weight into the
// edge list so agg kernels do ONE 8 B load per edge instead of the
// dependent chain csr[e] -> s -> dinv[s]. Bit-identical numerics.
__global__ __launch_bounds__(256) void fill_kernel(const int* __restrict__ src,
                                                   const int* __restrict__ dst,
                                                   const int* __restrict__ rs,
                                                   const float* __restrict__ dinv,
                                                   int* __restrict__ cur,
                                                   int2* __restrict__ csr2, int nE) {
    int e = blockIdx.x * 256 + threadIdx.x;
    if (e < nE) {
        int d = dst[e];
        int s = src[e];
        int p = rs[d] + atomicAdd(&cur[d], 1);
        csr2[p] = make_int2(s, __float_as_int(dinv[s]));
    }
}

// w1p[k*4 + {0,1,2,3}] = {W1[0][k], W1[1][k], W1[2][k], b1[k]}
__global__ __launch_bounds__(256) void pack_w1_kernel(const float* __restrict__ W1,
                                                      const float* __restrict__ b1,
                                                      float* __restrict__ w1p) {
    int k = blockIdx.x * 256 + threadIdx.x;
    if (k < 4096) {
        w1p[k * 4 + 0] = W1[k];
        w1p[k * 4 + 1] = W1[4096 + k];
        w1p[k * 4 + 2] = W1[8192 + k];
        w1p[k * 4 + 3] = b1[k];
    }
}

// Transpose-convert: Wt[n][k] = f16(W[k][n]); K, N multiples of 32.
__global__ __launch_bounds__(256) void tconv_kernel(const float* __restrict__ W,
                                                    f16* __restrict__ Wt,
                                                    int K, int N) {
    __shared__ float tile[32][33];
    int kb = blockIdx.y * 32, nb = blockIdx.x * 32;
    int tx = threadIdx.x & 31, ty = threadIdx.x >> 5;
    for (int r = ty; r < 32; r += 8)
        tile[r][tx] = W[(size_t)(kb + r) * N + nb + tx];
    __syncthreads();
    for (int r = ty; r < 32; r += 8)
        Wt[(size_t)(nb + r) * K + kb + tx] = (f16)tile[tx][r];
}

// ---------------------------------------------------------------------------
// fp32-input aggregation (widths 3, 64, 16)
// ---------------------------------------------------------------------------
template <int F, int TPN, bool RELU, bool BIAS, typename OutT>
__global__ __launch_bounds__(256) void agg_kernel(const float* __restrict__ t,
                                                  const float* __restrict__ dinv,
                                                  const int* __restrict__ rs,
                                                  const int2* __restrict__ csr2,
                                                  const float* __restrict__ bias,
                                                  OutT* __restrict__ out, int out_ld,
                                                  int nNodes) {
    constexpr int NPB = 256 / TPN;
    constexpr int C   = F / TPN;
    static_assert(TPN * C == F, "F must be TPN*C");
    int node = blockIdx.x * NPB + (int)threadIdx.x / TPN;
    if (node >= nNodes) return;
    int lane = (int)threadIdx.x % TPN;

    float acc[C];
#pragma unroll
    for (int c = 0; c < C; ++c) acc[c] = 0.f;

    int e0 = rs[node], e1 = rs[node + 1];
    for (int e = e0; e < e1; ++e) {
        int2 sw = csr2[e];
        int s = sw.x;
        float w = __int_as_float(sw.y);
        const float* tr = t + (size_t)s * F;
#pragma unroll
        for (int c = 0; c < C; ++c) acc[c] += w * tr[lane + c * TPN];
    }
    float di = dinv[node];
    const float* ti = t + (size_t)node * F;
    OutT* oi = out + (size_t)node * out_ld;
#pragma unroll
    for (int c = 0; c < C; ++c) {
        int col = lane + c * TPN;
        float v = di * acc[c] + di * di * ti[col];
        if (BIAS) v += bias[col];
        if (RELU) v = fmaxf(v, 0.f);
        storev(oi + col, v);
    }
}

// ---------------------------------------------------------------------------
// fp8 aggregation, F=1024, SINGLE PASS: 64 lanes/node (4 nodes/block), each
// lane loads a uint4 (16 B = 16 fp8 cols) per edge -> one VMEM instruction
// covers the whole 1 KB row per wave.
// ---------------------------------------------------------------------------
template <bool RELU>
__global__ __launch_bounds__(256) void agg_fp8_1024(const unsigned char* __restrict__ t,
                                                    const float* __restrict__ dinv,
                                                    const int* __restrict__ rs,
                                                    const int2* __restrict__ csr2,
                                                    const float* __restrict__ bias,
                                                    f16* __restrict__ out, int nNodes) {
    int node = blockIdx.x * 4 + ((int)threadIdx.x >> 6);
    if (node >= nNodes) return;
    int lane = (int)threadIdx.x & 63;

    float acc[16];
#pragma unroll
    for (int j = 0; j < 16; ++j) acc[j] = 0.f;

    int e0 = rs[node], e1 = rs[node + 1];
    int e = e0;
    for (; e + 1 < e1; e += 2) {
        int2 sw0 = csr2[e], sw1 = csr2[e + 1];
        float w0 = __int_as_float(sw0.y), w1 = __int_as_float(sw1.y);
        uint4 u0 = ((const uint4*)(t + (size_t)sw0.x * 1024))[lane];
        uint4 u1 = ((const uint4*)(t + (size_t)sw1.x * 1024))[lane];
        const unsigned int uw0[4] = {u0.x, u0.y, u0.z, u0.w};
        const unsigned int uw1[4] = {u1.x, u1.y, u1.z, u1.w};
#pragma unroll
        for (int q = 0; q < 4; ++q) {
            f32x2 l0 = __builtin_amdgcn_cvt_pk_f32_fp8((int)uw0[q], false);
            f32x2 h0 = __builtin_amdgcn_cvt_pk_f32_fp8((int)uw0[q], true);
            f32x2 l1 = __builtin_amdgcn_cvt_pk_f32_fp8((int)uw1[q], false);
            f32x2 h1 = __builtin_amdgcn_cvt_pk_f32_fp8((int)uw1[q], true);
            acc[q * 4 + 0] += w0 * l0.x + w1 * l1.x;
            acc[q * 4 + 1] += w0 * l0.y + w1 * l1.y;
            acc[q * 4 + 2] += w0 * h0.x + w1 * h1.x;
            acc[q * 4 + 3] += w0 * h0.y + w1 * h1.y;
        }
    }
    if (e < e1) {
        int2 sw0 = csr2[e];
        float w0 = __int_as_float(sw0.y);
        uint4 u0 = ((const uint4*)(t + (size_t)sw0.x * 1024))[lane];
        const unsigned int uw0[4] = {u0.x, u0.y, u0.z, u0.w};
#pragma unroll
        for (int q = 0; q < 4; ++q) {
            f32x2 l0 = __builtin_amdgcn_cvt_pk_f32_fp8((int)uw0[q], false);
            f32x2 h0 = __builtin_amdgcn_cvt_pk_f32_fp8((int)uw0[q], true);
            acc[q * 4 + 0] += w0 * l0.x;
            acc[q * 4 + 1] += w0 * l0.y;
            acc[q * 4 + 2] += w0 * h0.x;
            acc[q * 4 + 3] += w0 * h0.y;
        }
    }
    float di = dinv[node], di2 = di * di;
    uint4 us = ((const uint4*)(t + (size_t)node * 1024))[lane];
    const unsigned int uws[4] = {us.x, us.y, us.z, us.w};
    Pack8 o0, o1;
#pragma unroll
    for (int q = 0; q < 4; ++q) {
        f32x2 sl = __builtin_amdgcn_cvt_pk_f32_fp8((int)uws[q], false);
        f32x2 sh = __builtin_amdgcn_cvt_pk_f32_fp8((int)uws[q], true);
        float4 b = *(const float4*)(bias + 16 * lane + q * 4);
        float v0 = di * acc[q * 4 + 0] + di2 * sl.x + b.x;
        float v1 = di * acc[q * 4 + 1] + di2 * sl.y + b.y;
        float v2 = di * acc[q * 4 + 2] + di2 * sh.x + b.z;
        float v3 = di * acc[q * 4 + 3] + di2 * sh.y + b.w;
        if (RELU) {
            v0 = fmaxf(v0, 0.f); v1 = fmaxf(v1, 0.f);
            v2 = fmaxf(v2, 0.f); v3 = fmaxf(v3, 0.f);
        }
        Pack8& dst8 = (q < 2) ? o0 : o1;
        int base = (q & 1) * 4;
        dst8.h[base + 0] = (f16)v0;
        dst8.h[base + 1] = (f16)v1;
        dst8.h[base + 2] = (f16)v2;
        dst8.h[base + 3] = (f16)v3;
    }
    uint4* orow = (uint4*)(out + (size_t)node * 1024 + 16 * lane);
    orow[0] = o0.v;
    orow[1] = o1.v;
}

// ---------------------------------------------------------------------------
// fp8 aggregation over a 256-col tensor (layer 3): 64 lanes/node, one uint
// (4 fp8 cols) per lane per edge. Round-8-proven structure.
// ---------------------------------------------------------------------------
template <bool RELU>
__global__ __launch_bounds__(256) void agg_fp8_256(const unsigned char* __restrict__ t,
                                                   int in_ld,
                                                   const float* __restrict__ dinv,
                                                   const int* __restrict__ rs,
                                                   const int2* __restrict__ csr2,
                                                   const float* __restrict__ bias,
                                                   f16* __restrict__ out,
                                                   int out_ld, int nNodes) {
    int node = blockIdx.x * 4 + ((int)threadIdx.x >> 6);
    if (node >= nNodes) return;
    int lane = (int)threadIdx.x & 63;

    float acc0 = 0.f, acc1 = 0.f, acc2 = 0.f, acc3 = 0.f;
    int e0 = rs[node], e1 = rs[node + 1];
    int e = e0;
    for (; e + 1 < e1; e += 2) {
        int2 sw0 = csr2[e], sw1 = csr2[e + 1];
        float w0 = __int_as_float(sw0.y), w1 = __int_as_float(sw1.y);
        unsigned int u0 = ((const unsigned int*)(t + (size_t)sw0.x * in_ld))[lane];
        unsigned int u1 = ((const unsigned int*)(t + (size_t)sw1.x * in_ld))[lane];
        f32x2 l0 = __builtin_amdgcn_cvt_pk_f32_fp8((int)u0, false);
        f32x2 h0 = __builtin_amdgcn_cvt_pk_f32_fp8((int)u0, true);
        f32x2 l1 = __builtin_amdgcn_cvt_pk_f32_fp8((int)u1, false);
        f32x2 h1 = __builtin_amdgcn_cvt_pk_f32_fp8((int)u1, true);
        acc0 += w0 * l0.x + w1 * l1.x;
        acc1 += w0 * l0.y + w1 * l1.y;
        acc2 += w0 * h0.x + w1 * h1.x;
        acc3 += w0 * h0.y + w1 * h1.y;
    }
    if (e < e1) {
        int2 sw0 = csr2[e];
        float w0 = __int_as_float(sw0.y);
        unsigned int u0 = ((const unsigned int*)(t + (size_t)sw0.x * in_ld))[lane];
        f32x2 l0 = __builtin_amdgcn_cvt_pk_f32_fp8((int)u0, false);
        f32x2 h0 = __builtin_amdgcn_cvt_pk_f32_fp8((int)u0, true);
        acc0 += w0 * l0.x;
        acc1 += w0 * l0.y;
        acc2 += w0 * h0.x;
        acc3 += w0 * h0.y;
    }
    float di = dinv[node], di2 = di * di;
    unsigned int us = ((const unsigned int*)(t + (size_t)node * in_ld))[lane];
    f32x2 sl = __builtin_amdgcn_cvt_pk_f32_fp8((int)us, false);
    f32x2 sh = __builtin_amdgcn_cvt_pk_f32_fp8((int)us, true);
    float4 b = *(const float4*)(bias + 4 * lane);
    float v0 = di * acc0 + di2 * sl.x + b.x;
    float v1 = di * acc1 + di2 * sl.y + b.y;
    float v2 = di * acc2 + di2 * sh.x + b.z;
    float v3 = di * acc3 + di2 * sh.y + b.w;
    if (RELU) {
        v0 = fmaxf(v0, 0.f); v1 = fmaxf(v1, 0.f);
        v2 = fmaxf(v2, 0.f); v3 = fmaxf(v3, 0.f);
    }
    Pack4 pk;
    pk.h[0] = (f16)v0; pk.h[1] = (f16)v1; pk.h[2] = (f16)v2; pk.h[3] = (f16)v3;
    *(uint2*)(out + (size_t)node * out_ld + 4 * lane) = pk.v;
}

// ---------------------------------------------------------------------------
// MFMA GEMM kernels. LDS row stride 40 f16 = 80 B (16 B-aligned).
// Fragments: A[m=lane&15][k=(lane>>4)*8+j]; B^T rows; C/D col=lane&15,
// row=(lane>>4)*4+reg.
// ---------------------------------------------------------------------------
#define LDSTR 40

// Fused layer1+2 (mfma10, measured 735 us in r8 — BEST; restored verbatim).
// Double-buffered LDSTR-40 LDS, ONE barrier per K-step, B one-K-step-ahead
// register prefetch. r10's DMA variant (953 us) regressed because
// __syncthreads drains vmcnt(0) including the JUST-ISSUED next-tile DMA;
// register prefetch survives the barrier, LDS-destined DMA does not.
// 2-phase exploration closed: {fewer barriers, conflict-free LDS, DMA
// staging, tile geometry} all tested; 735 us is this structure's ceiling.
__global__ __launch_bounds__(512, 4) void gemm12_mfma10(const float* __restrict__ aggx,
                                                        const float* __restrict__ w1p,
                                                        const f16* __restrict__ Bt,
                                                        unsigned char* __restrict__ t2) {
    __shared__ f16 As[2 * 128 * LDSTR] __attribute__((aligned(16)));
    __shared__ f16 Bs[2 * 256 * LDSTR] __attribute__((aligned(16)));
    int tid = threadIdx.x;
    int m0  = blockIdx.x * 128;
    int n0c = blockIdx.y * 256;  // column chunk base in W2

    // A-recompute: 2 m-rows x 4 k per thread (64 row-pairs x 8 k-groups)
    int mg = tid >> 3;   // 0..63 -> rows 2mg, 2mg+1
    int kg = tid & 7;    // k group: kg*4 .. kg*4+3
    float a0[2], a1[2], a2[2];
#pragma unroll
    for (int j = 0; j < 2; ++j) {
        int gm = m0 + mg * 2 + j;
        if (gm < NN) {
            a0[j] = aggx[gm * 3 + 0];
            a1[j] = aggx[gm * 3 + 1];
            a2[j] = aggx[gm * 3 + 2];
        } else {
            a0[j] = a1[j] = a2[j] = 0.f;
        }
    }

    // B staging: 2 threads per n-row, 16 f16 each
    int brow = tid >> 1;            // 0..255
    int bkof = (tid & 1) * 16;
    const f16* bbase = Bt + (size_t)(n0c + brow) * 4096 + bkof;

    int lane   = tid & 63;
    int wv     = tid >> 6;          // 0..7
    int wm     = (wv >> 2) * 64;    // 0 or 64
    int wn     = (wv & 3) * 64;     // 0,64,128,192
    int fr_m   = lane & 15;
    int khalf8 = (lane >> 4) * 8;

    // A-stage helper (r0 body, parameterized destination buffer + k)
    auto stageA = [&](f16* dstAs, int kk) {
        int kb = kk + kg * 4;
        float4 wk0 = *(const float4*)(w1p + (size_t)(kb + 0) * 4);
        float4 wk1 = *(const float4*)(w1p + (size_t)(kb + 1) * 4);
        float4 wk2 = *(const float4*)(w1p + (size_t)(kb + 2) * 4);
        float4 wk3 = *(const float4*)(w1p + (size_t)(kb + 3) * 4);
#pragma unroll
        for (int j = 0; j < 2; ++j) {
            float h0 = fmaxf(a0[j] * wk0.x + a1[j] * wk0.y + a2[j] * wk0.z + wk0.w, 0.f);
            float h1 = fmaxf(a0[j] * wk1.x + a1[j] * wk1.y + a2[j] * wk1.z + wk1.w, 0.f);
            float h2 = fmaxf(a0[j] * wk2.x + a1[j] * wk2.y + a2[j] * wk2.z + wk2.w, 0.f);
            float h3 = fmaxf(a0[j] * wk3.x + a1[j] * wk3.y + a2[j] * wk3.z + wk3.w, 0.f);
            Pack4 pk;
            pk.h[0] = (f16)h0; pk.h[1] = (f16)h1; pk.h[2] = (f16)h2; pk.h[3] = (f16)h3;
            *(uint2*)(&dstAs[(mg * 2 + j) * LDSTR + kg * 4]) = pk.v;
        }
    };

    // ---- prologue: stage buffer 0 with k=0; load B regs for k=32 ----
    h8 pb0 = *(const h8*)(bbase);
    h8 pb1 = *(const h8*)(bbase + 8);
    stageA(As, 0);
    *(h8*)(&Bs[brow * LDSTR + bkof]) = pb0;
    *(h8*)(&Bs[brow * LDSTR + bkof + 8]) = pb1;
    pb0 = *(const h8*)(bbase + 32);
    pb1 = *(const h8*)(bbase + 32 + 8);

    f32x4 acc[4][4];
#pragma unroll
    for (int i = 0; i < 4; ++i)
#pragma unroll
        for (int j = 0; j < 4; ++j) acc[i][j] = (f32x4){0.f, 0.f, 0.f, 0.f};

    int p = 0;
    for (int k0 = 0; k0 < 4096; k0 += 32) {
        __syncthreads();  // buf[p] fully staged; all reads of buf[p^1] done
        const f16* Asc = As + p * (128 * LDSTR);
        const f16* Bsc = Bs + p * (256 * LDSTR);
        f16* Asn = As + (p ^ 1) * (128 * LDSTR);
        f16* Bsn = Bs + (p ^ 1) * (256 * LDSTR);

        // ---- stage NEXT K-tile into buf[p^1] (overlaps other waves' MFMA) ----
        int k1 = k0 + 32;
        if (k1 < 4096) {
            *(h8*)(&Bsn[brow * LDSTR + bkof]) = pb0;
            *(h8*)(&Bsn[brow * LDSTR + bkof + 8]) = pb1;
            stageA(Asn, k1);
        }

        // ---- frag reads from current buffer ----
        h8 af[4];
#pragma unroll
        for (int mt = 0; mt < 4; ++mt)
            af[mt] = *(const h8*)(&Asc[(wm + mt * 16 + fr_m) * LDSTR + khalf8]);

        // ---- prefetch B for k+64 (drains under MFMA phase) ----
        int k2 = k0 + 64;
        if (k2 < 4096) {
            pb0 = *(const h8*)(bbase + k2);
            pb1 = *(const h8*)(bbase + k2 + 8);
        }

#pragma unroll
        for (int nt = 0; nt < 4; ++nt) {
            h8 bf = *(const h8*)(&Bsc[(wn + nt * 16 + fr_m) * LDSTR + khalf8]);
#pragma unroll
            for (int mt = 0; mt < 4; ++mt)
                acc[mt][nt] = __builtin_amdgcn_mfma_f32_16x16x32_f16(af[mt], bf, acc[mt][nt], 0, 0, 0);
        }
        p ^= 1;
    }

#pragma unroll
    for (int mt = 0; mt < 4; ++mt) {
#pragma unroll
        for (int reg = 0; reg < 4; ++reg) {
            int gm = m0 + wm + mt * 16 + (lane >> 4) * 4 + reg;
            if (gm < NN) {
                unsigned char* orow = t2 + (size_t)gm * 1024 + n0c + wn + fr_m;
#pragma unroll
                for (int nt = 0; nt < 4; ++nt)
                    orow[nt * 16] = f2fp8(acc[mt][nt][reg]);
            }
        }
    }
}

// Generic MFMA GEMM (layer 3): C(fp8)[M,ldc] = A[M,lda](f16) @ Bt[N][K](f16)^T
// 128x128 tile, register-prefetched staging. 20.5 KB LDS -> 8 blocks/CU.
__global__ __launch_bounds__(256) void gemm_mfma(const f16* __restrict__ A, int lda,
                                                 const f16* __restrict__ Bt, int K,
                                                 unsigned char* __restrict__ C, int ldc,
                                                 int M) {
    __shared__ f16 As[128 * LDSTR] __attribute__((aligned(16)));
    __shared__ f16 Bs[128 * LDSTR] __attribute__((aligned(16)));
    int tid = threadIdx.x;
    int m0 = blockIdx.y * 128;
    int n0 = blockIdx.x * 128;

    int row = tid >> 1;
    int kof = (tid & 1) * 16;
    int am  = m0 + row;
    if (am > M - 1) am = M - 1;

    int lane   = tid & 63;
    int wv     = tid >> 6;
    int fr_m   = lane & 15;
    int khalf8 = (lane >> 4) * 8;

    const f16* abase = A + (size_t)am * lda + kof;
    const f16* bbase = Bt + (size_t)(n0 + row) * K + kof;

    h8 pa0 = *(const h8*)(abase);
    h8 pa1 = *(const h8*)(abase + 8);
    h8 pb0 = *(const h8*)(bbase);
    h8 pb1 = *(const h8*)(bbase + 8);

    f32x4 acc[2][8];
#pragma unroll
    for (int i = 0; i < 2; ++i)
#pragma unroll
        for (int j = 0; j < 8; ++j) acc[i][j] = (f32x4){0.f, 0.f, 0.f, 0.f};

    for (int k0 = 0; k0 < K; k0 += 32) {
        *(h8*)(&As[row * LDSTR + kof]) = pa0;
        *(h8*)(&As[row * LDSTR + kof + 8]) = pa1;
        *(h8*)(&Bs[row * LDSTR + kof]) = pb0;
        *(h8*)(&Bs[row * LDSTR + kof + 8]) = pb1;
        __syncthreads();

        int kn = k0 + 32;
        if (kn < K) {
            pa0 = *(const h8*)(abase + kn);
            pa1 = *(const h8*)(abase + kn + 8);
            pb0 = *(const h8*)(bbase + kn);
            pb1 = *(const h8*)(bbase + kn + 8);
        }

        h8 af0 = *(const h8*)(&As[(wv * 32 + fr_m) * LDSTR + khalf8]);
        h8 af1 = *(const h8*)(&As[(wv * 32 + 16 + fr_m) * LDSTR + khalf8]);
#pragma unroll
        for (int nt = 0; nt < 8; ++nt) {
            h8 bf = *(const h8*)(&Bs[(nt * 16 + fr_m) * LDSTR + khalf8]);
            acc[0][nt] = __builtin_amdgcn_mfma_f32_16x16x32_f16(af0, bf, acc[0][nt], 0, 0, 0);
            acc[1][nt] = __builtin_amdgcn_mfma_f32_16x16x32_f16(af1, bf, acc[1][nt], 0, 0, 0);
        }
        __syncthreads();
    }

#pragma unroll
    for (int mt = 0; mt < 2; ++mt) {
#pragma unroll
        for (int reg = 0; reg < 4; ++reg) {
            int gm = m0 + wv * 32 + mt * 16 + (lane >> 4) * 4 + reg;
            if (gm < M) {
                unsigned char* orow = C + (size_t)gm * ldc + n0 + fr_m;
#pragma unroll
                for (int nt = 0; nt < 8; ++nt)
                    orow[nt * 16] = f2fp8(acc[mt][nt][reg]);
            }
        }
    }
}

// ---------------------------------------------------------------------------
// Layer-4 GEMM: C[M,64] f32 = A[M,256](f16) @ B[256,64](f32)
// ---------------------------------------------------------------------------
#define BM 64
#define BN 64
#define BKS 16
__global__ __launch_bounds__(256) void gemm_f16A_kernel(const f16* __restrict__ A,
                                                        const float* __restrict__ B,
                                                        float* __restrict__ C,
                                                        int M, int K, int N) {
    __shared__ float As[BKS][BM + 4];
    __shared__ float Bs[BKS][BN + 4];
    int tid = threadIdx.x;
    int tx = tid & 15;
    int ty = tid >> 4;
    int m0 = blockIdx.y * BM;
    int n0 = blockIdx.x * BN;

    float acc[4][4];
#pragma unroll
    for (int i = 0; i < 4; ++i)
#pragma unroll
        for (int j = 0; j < 4; ++j) acc[i][j] = 0.f;

    int lmA = tid >> 2;
    int lkA = (tid & 3) * 4;
    int lkB = tid >> 4;
    int lnB = (tid & 15) * 4;

    for (int k0 = 0; k0 < K; k0 += BKS) {
        int gm = m0 + lmA;
        if (gm > M - 1) gm = M - 1;
        h4v av = *(const h4v*)(A + (size_t)gm * K + k0 + lkA);
        As[lkA + 0][lmA] = (float)av.x;
        As[lkA + 1][lmA] = (float)av.y;
        As[lkA + 2][lmA] = (float)av.z;
        As[lkA + 3][lmA] = (float)av.w;
        float4 bv = *reinterpret_cast<const float4*>(B + (size_t)(k0 + lkB) * N + n0 + lnB);
        *reinterpret_cast<float4*>(&Bs[lkB][lnB]) = bv;
        __syncthreads();

#pragma unroll
        for (int k = 0; k < BKS; ++k) {
            float4 a4 = *reinterpret_cast<const float4*>(&As[k][ty * 4]);
            float4 b4 = *reinterpret_cast<const float4*>(&Bs[k][tx * 4]);
            float a[4] = {a4.x, a4.y, a4.z, a4.w};
            float b[4] = {b4.x, b4.y, b4.z, b4.w};
#pragma unroll
            for (int i = 0; i < 4; ++i)
#pragma unroll
                for (int j = 0; j < 4; ++j) acc[i][j] += a[i] * b[j];
        }
        __syncthreads();
    }

#pragma unroll
    for (int i = 0; i < 4; ++i) {
        int m = m0 + ty * 4 + i;
        if (m < M) {
            float4 o = make_float4(acc[i][0], acc[i][1], acc[i][2], acc[i][3]);
            *reinterpret_cast<float4*>(C + (size_t)m * N + n0 + tx * 4) = o;
        }
    }
}

// Layer-5 GEMM: t5 = h4[NN,64](f16) @ W5[64,16](f32)
__global__ __launch_bounds__(256) void gemm5_kernel(const f16* __restrict__ h4,
                                                    const float* __restrict__ W5,
                                                    float* __restrict__ t5, int nNodes) {
    int idx = blockIdx.x * 256 + threadIdx.x;
    int i = idx >> 4, j = idx & 15;
    if (i >= nNodes) return;
    const f16* a = h4 + (size_t)i * 64;
    float s = 0.f;
#pragma unroll
    for (int k = 0; k < 64; ++k) s += (float)a[k] * W5[k * 16 + j];
    t5[idx] = s;
}

// Pool + classifier
__global__ __launch_bounds__(256) void pool_kernel(const float* __restrict__ h5,
                                                   float* __restrict__ pool) {
    __shared__ float red[256];
    int c = blockIdx.x;
    float s = 0.f;
    for (int i = threadIdx.x; i < NN; i += 256) s += h5[(size_t)i * 16 + c];
    red[threadIdx.x] = s;
    __syncthreads();
    for (int off = 128; off > 0; off >>= 1) {
        if ((int)threadIdx.x < off) red[threadIdx.x] += red[threadIdx.x + off];
        __syncthreads();
    }
    if (threadIdx.x == 0) pool[c] = red[0];
}

__global__ void final_kernel(const float* __restrict__ pool, const float* __restrict__ Wl,
                             const float* __restrict__ bl, float* __restrict__ out) {
    int j = threadIdx.x;
    if (j < 3) {
        float s = 0.f;
#pragma unroll
        for (int c = 0; c < 16; ++c) s += pool[c] * Wl[c * 3 + j];
        out[j] = s * (1.0f / (float)NN) + bl[j];
    }
}

// ---------------------------------------------------------------------------
// Host launcher — workspace ledger ~212 MB (csr2 int2 replaces csr int).
// ---------------------------------------------------------------------------
extern "C" void kernel_launch(void* const* d_in, const int* in_sizes, int n_in,
                              void* d_out, int out_size, void* d_ws, size_t ws_size,
                              hipStream_t stream) {
    (void)in_sizes; (void)n_in; (void)out_size; (void)ws_size;

    const float* x  = (const float*)d_in[0];
    const int*   ei = (const int*)d_in[1];
    const float* W1 = (const float*)d_in[2];
    const float* b1 = (const float*)d_in[3];
    const float* W2 = (const float*)d_in[4];
    const float* b2 = (const float*)d_in[5];
    const float* W3 = (const float*)d_in[6];
    const float* b3 = (const float*)d_in[7];
    const float* W4 = (const float*)d_in[8];
    const float* b4 = (const float*)d_in[9];
    const float* W5 = (const float*)d_in[10];
    const float* b5 = (const float*)d_in[11];
    const float* Wl = (const float*)d_in[12];
    const float* bl = (const float*)d_in[13];
    float* out = (float*)d_out;

    const int* srcp = ei;
    const int* dstp = ei + NE;

    char* p = (char*)d_ws;
    auto carve = [&](size_t bytes) {
        char* r = p;
        p += (bytes + 255) & ~(size_t)255;
        return r;
    };
    int*   deg  = (int*)carve(NN * 4);
    int*   cur  = (int*)carve(NN * 4);
    int*   rs   = (int*)carve((NN + 1) * 4);
    int*   bsum = (int*)carve(256 * 4);
    int2*  csr2 = (int2*)carve((size_t)NE * 8);              // 12.8 MB
    float* dinv = (float*)carve(NN * 4);
    float* aggx = (float*)carve((size_t)NN * 3 * 4);
    float* pool = (float*)carve(16 * 4);
    float* w1p  = (float*)carve((size_t)4096 * 4 * 4);       // 64 KB
    f16*   w2t  = (f16*)carve((size_t)1024 * 4096 * 2);      // 8.4 MB
    f16*   w3t  = (f16*)carve((size_t)256 * 1024 * 2);       // 0.5 MB
    unsigned char* tbuf = (unsigned char*)carve((size_t)NN * 1024);  // 51.2 MB: fp8 t2[NN,1024] / t3 / f32 t4,t5 view
    f16*   h2   = (f16*)carve((size_t)NN * 1024 * 2);        // 102.4 MB
    f16*   h3   = (f16*)carve((size_t)NN * 256 * 2);         // 25.6 MB
    f16*   h4   = (f16*)carve((size_t)NN * 64 * 2);          // 6.4 MB
    float* h5   = (float*)carve((size_t)NN * 16 * 4);        // 3.2 MB
    float* tf32 = (float*)tbuf;                              // f32 view for t4/t5

    const int NB = (NN + 255) / 256;  // 196

    zero_int_kernel<<<NB, 256, 0, stream>>>(deg, NN);
    zero_int_kernel<<<NB, 256, 0, stream>>>(cur, NN);
    count_kernel<<<(NE + 255) / 256, 256, 0, stream>>>(dstp, deg, NE);
    dinv_kernel<<<NB, 256, 0, stream>>>(deg, dinv, NN);
    scan1_kernel<<<NB, 256, 0, stream>>>(deg, rs, bsum, NN);
    scan2_kernel<<<1, 256, 0, stream>>>(bsum, rs, NB, NN);
    scan3_kernel<<<NB, 256, 0, stream>>>(rs, bsum, NN);
    fill_kernel<<<(NE + 255) / 256, 256, 0, stream>>>(srcp, dstp, rs, dinv, cur, csr2, NE);

    // Weight prep
    pack_w1_kernel<<<16, 256, 0, stream>>>(W1, b1, w1p);
    tconv_kernel<<<dim3(1024 / 32, 4096 / 32), 256, 0, stream>>>(W2, w2t, 4096, 1024);
    tconv_kernel<<<dim3(256 / 32, 1024 / 32), 256, 0, stream>>>(W3, w3t, 1024, 256);

    // aggx = A_hat @ x (width 3, fp32)
    agg_kernel<3, 1, false, false, float><<<NB, 256, 0, stream>>>(
        x, dinv, rs, csr2, nullptr, aggx, 3, NN);

    const int MB2 = (NN + 127) / 128;  // 391

    // Layers 1+2 fused: one 512-thread MFMA launch for all 1024 cols (fp8 out)
    gemm12_mfma10<<<dim3(MB2, 4), 512, 0, stream>>>(aggx, w1p, w2t, tbuf);
    // h2 = relu(A_hat t2 + b2): ONE pass, uint4/lane (16 B) per edge
    agg_fp8_1024<true><<<(NN + 3) / 4, 256, 0, stream>>>(
        tbuf, dinv, rs, csr2, b2, h2, NN);

    // Layer 3 (MFMA, fp8 out): t3 = h2 @ W3; h3 = relu(A_hat t3 + b3)
    gemm_mfma<<<dim3(2, MB2), 256, 0, stream>>>(
        h2, 1024, w3t, 1024, tbuf, 256, NN);
    agg_fp8_256<true><<<(NN + 3) / 4, 256, 0, stream>>>(
        tbuf, 256, dinv, rs, csr2, b3, h3, 256, NN);

    // Layer 4: t4 = h3 @ W4 [NN,64] f32; h4 = relu(A_hat t4 + b4) -> f16
    gemm_f16A_kernel<<<dim3(1, (NN + BM - 1) / BM), 256, 0, stream>>>(
        h3, W4, tf32, NN, 256, 64);
    agg_kernel<64, 64, true, true, f16><<<(NN + 3) / 4, 256, 0, stream>>>(
        tf32, dinv, rs, csr2, b4, h4, 64, NN);

    // Layer 5: t5 = h4 @ W5 [NN,16] f32; h5 = A_hat t5 + b5 (no relu)
    gemm5_kernel<<<(NN * 16 + 255) / 256, 256, 0, stream>>>(h4, W5, tf32, NN);
    agg_kernel<16, 16, false, true, float><<<(NN + 15) / 16, 256, 0, stream>>>(
        tf32, dinv, rs, csr2, b5, h5, 16, NN);

    // Global mean pool + classifier
    pool_kernel<<<16, 256, 0, stream>>>(h5, pool);
    final_kernel<<<1, 64, 0, stream>>>(pool, Wl, bl, out);
}

// Round 12
// 1569.852 us; speedup vs baseline: 1.1588x; 1.0260x over previous
//
#include <hip/hip_runtime.h>
#include <stdint.h>

#define NN 50000
#define NE 1600000

typedef _Float16 f16;
typedef __attribute__((ext_vector_type(8))) _Float16 h8;
typedef __attribute__((ext_vector_type(4))) _Float16 h4v;
typedef __attribute__((ext_vector_type(4))) float f32x4;
typedef __attribute__((ext_vector_type(2))) float f32x2;

union PackU { unsigned int u; f16 h[2]; };
union Pack4 { uint2 v; f16 h[4]; };
union Pack8 { uint4 v; f16 h[8]; };

__device__ __forceinline__ void storev(float* p, float v) { *p = v; }
__device__ __forceinline__ void storev(f16* p, float v) { *p = (f16)v; }

__device__ __forceinline__ unsigned char f2fp8(float v) {
    int pk = __builtin_amdgcn_cvt_pk_fp8_f32(v, v, 0, false);
    return (unsigned char)(pk & 0xff);
}

// ---------------------------------------------------------------------------
// Preprocessing
// ---------------------------------------------------------------------------
__global__ __launch_bounds__(256) void zero_int_kernel(int* __restrict__ p, int n) {
    int i = blockIdx.x * 256 + threadIdx.x;
    if (i < n) p[i] = 0;
}

__global__ __launch_bounds__(256) void count_kernel(const int* __restrict__ dst,
                                                    int* __restrict__ deg, int nE) {
    int e = blockIdx.x * 256 + threadIdx.x;
    if (e < nE) atomicAdd(&deg[dst[e]], 1);
}

__global__ __launch_bounds__(256) void dinv_kernel(const int* __restrict__ deg,
                                                   float* __restrict__ dinv, int n) {
    int i = blockIdx.x * 256 + threadIdx.x;
    if (i < n) dinv[i] = rsqrtf((float)deg[i] + 1.0f);
}

// Parallel 3-phase exclusive scan over 50000 ints (196 blocks of 256).
__global__ __launch_bounds__(256) void scan1_kernel(const int* __restrict__ cnt,
                                                    int* __restrict__ rs,
                                                    int* __restrict__ bsum, int n) {
    __shared__ int sm[256];
    int b = blockIdx.x, t = threadIdx.x, i = b * 256 + t;
    int v = (i < n) ? cnt[i] : 0;
    sm[t] = v;
    __syncthreads();
    for (int off = 1; off < 256; off <<= 1) {
        int x = 0;
        if (t >= off) x = sm[t - off];
        __syncthreads();
        if (t >= off) sm[t] += x;
        __syncthreads();
    }
    if (i < n) rs[i] = sm[t] - v;  // block-local exclusive
    if (t == 255) bsum[b] = sm[255];
}

__global__ __launch_bounds__(256) void scan2_kernel(int* __restrict__ bsum,
                                                    int* __restrict__ rs, int nb, int n) {
    __shared__ int sm[256];
    int t = threadIdx.x;
    int v = (t < nb) ? bsum[t] : 0;
    sm[t] = v;
    __syncthreads();
    for (int off = 1; off < 256; off <<= 1) {
        int x = 0;
        if (t >= off) x = sm[t - off];
        __syncthreads();
        if (t >= off) sm[t] += x;
        __syncthreads();
    }
    if (t < nb) bsum[t] = sm[t] - v;  // exclusive block offsets
    if (t == 255) rs[n] = sm[255];    // grand total (= nE)
}

__global__ __launch_bounds__(256) void scan3_kernel(int* __restrict__ rs,
                                                    const int* __restrict__ bsum, int n) {
    int i = blockIdx.x * 256 + threadIdx.x;
    if (i < n) rs[i] += bsum[blockIdx.x];
}

__global__ __launch_bounds__(256) void fill_kernel(const int* __restrict__ src,
                                                   const int* __restrict__ dst,
                                                   const int* __restrict__ rs,
                                                   int* __restrict__ cur,
                                                   int* __restrict__ csr, int nE) {
    int e = blockIdx.x * 256 + threadIdx.x;
    if (e < nE) {
        int d = dst[e];
        int p = rs[d] + atomicAdd(&cur[d], 1);
        csr[p] = src[e];
    }
}

// w1p[k*4 + {0,1,2,3}] = {W1[0][k], W1[1][k], W1[2][k], b1[k]}
__global__ __launch_bounds__(256) void pack_w1_kernel(const float* __restrict__ W1,
                                                      const float* __restrict__ b1,
                                                      float* __restrict__ w1p) {
    int k = blockIdx.x * 256 + threadIdx.x;
    if (k < 4096) {
        w1p[k * 4 + 0] = W1[k];
        w1p[k * 4 + 1] = W1[4096 + k];
        w1p[k * 4 + 2] = W1[8192 + k];
        w1p[k * 4 + 3] = b1[k];
    }
}

// Transpose-convert: Wt[n][k] = f16(W[k][n]); K, N multiples of 32.
__global__ __launch_bounds__(256) void tconv_kernel(const float* __restrict__ W,
                                                    f16* __restrict__ Wt,
                                                    int K, int N) {
    __shared__ float tile[32][33];
    int kb = blockIdx.y * 32, nb = blockIdx.x * 32;
    int tx = threadIdx.x & 31, ty = threadIdx.x >> 5;
    for (int r = ty; r < 32; r += 8)
        tile[r][tx] = W[(size_t)(kb + r) * N + nb + tx];
    __syncthreads();
    for (int r = ty; r < 32; r += 8)
        Wt[(size_t)(nb + r) * K + kb + tx] = (f16)tile[tx][r];
}

// ---------------------------------------------------------------------------
// Input-typed aggregation (widths 3, 64, 16). InT = float or f16; the f16
// path halves gather bytes/edge for layers 4/5 (pipeline already tolerates
// fp8 intermediates t2/t3, so f16 t4/t5 noise is negligible after pooling).
// ---------------------------------------------------------------------------
template <int F, int TPN, bool RELU, bool BIAS, typename InT, typename OutT>
__global__ __launch_bounds__(256) void agg_kernel(const InT* __restrict__ t,
                                                  const float* __restrict__ dinv,
                                                  const int* __restrict__ rs,
                                                  const int* __restrict__ csr,
                                                  const float* __restrict__ bias,
                                                  OutT* __restrict__ out, int out_ld,
                                                  int nNodes) {
    constexpr int NPB = 256 / TPN;
    constexpr int C   = F / TPN;
    static_assert(TPN * C == F, "F must be TPN*C");
    int node = blockIdx.x * NPB + (int)threadIdx.x / TPN;
    if (node >= nNodes) return;
    int lane = (int)threadIdx.x % TPN;

    float acc[C];
#pragma unroll
    for (int c = 0; c < C; ++c) acc[c] = 0.f;

    int e0 = rs[node], e1 = rs[node + 1];
    for (int e = e0; e < e1; ++e) {
        int s = csr[e];
        float w = dinv[s];
        const InT* tr = t + (size_t)s * F;
#pragma unroll
        for (int c = 0; c < C; ++c) acc[c] += w * (float)tr[lane + c * TPN];
    }
    float di = dinv[node];
    const InT* ti = t + (size_t)node * F;
    OutT* oi = out + (size_t)node * out_ld;
#pragma unroll
    for (int c = 0; c < C; ++c) {
        int col = lane + c * TPN;
        float v = di * acc[c] + di * di * (float)ti[col];
        if (BIAS) v += bias[col];
        if (RELU) v = fmaxf(v, 0.f);
        storev(oi + col, v);
    }
}

// ---------------------------------------------------------------------------
// fp8 aggregation, F=1024, SINGLE PASS: 64 lanes/node (4 nodes/block), each
// lane loads a uint4 (16 B = 16 fp8 cols) per edge -> one VMEM instruction
// covers the whole 1 KB row per wave.
// ---------------------------------------------------------------------------
template <bool RELU>
__global__ __launch_bounds__(256) void agg_fp8_1024(const unsigned char* __restrict__ t,
                                                    const float* __restrict__ dinv,
                                                    const int* __restrict__ rs,
                                                    const int* __restrict__ csr,
                                                    const float* __restrict__ bias,
                                                    f16* __restrict__ out, int nNodes) {
    int node = blockIdx.x * 4 + ((int)threadIdx.x >> 6);
    if (node >= nNodes) return;
    int lane = (int)threadIdx.x & 63;

    float acc[16];
#pragma unroll
    for (int j = 0; j < 16; ++j) acc[j] = 0.f;

    int e0 = rs[node], e1 = rs[node + 1];
    int e = e0;
    for (; e + 1 < e1; e += 2) {
        int s0 = csr[e], s1 = csr[e + 1];
        float w0 = dinv[s0], w1 = dinv[s1];
        uint4 u0 = ((const uint4*)(t + (size_t)s0 * 1024))[lane];
        uint4 u1 = ((const uint4*)(t + (size_t)s1 * 1024))[lane];
        const unsigned int uw0[4] = {u0.x, u0.y, u0.z, u0.w};
        const unsigned int uw1[4] = {u1.x, u1.y, u1.z, u1.w};
#pragma unroll
        for (int q = 0; q < 4; ++q) {
            f32x2 l0 = __builtin_amdgcn_cvt_pk_f32_fp8((int)uw0[q], false);
            f32x2 h0 = __builtin_amdgcn_cvt_pk_f32_fp8((int)uw0[q], true);
            f32x2 l1 = __builtin_amdgcn_cvt_pk_f32_fp8((int)uw1[q], false);
            f32x2 h1 = __builtin_amdgcn_cvt_pk_f32_fp8((int)uw1[q], true);
            acc[q * 4 + 0] += w0 * l0.x + w1 * l1.x;
            acc[q * 4 + 1] += w0 * l0.y + w1 * l1.y;
            acc[q * 4 + 2] += w0 * h0.x + w1 * h1.x;
            acc[q * 4 + 3] += w0 * h0.y + w1 * h1.y;
        }
    }
    if (e < e1) {
        int s0 = csr[e];
        float w0 = dinv[s0];
        uint4 u0 = ((const uint4*)(t + (size_t)s0 * 1024))[lane];
        const unsigned int uw0[4] = {u0.x, u0.y, u0.z, u0.w};
#pragma unroll
        for (int q = 0; q < 4; ++q) {
            f32x2 l0 = __builtin_amdgcn_cvt_pk_f32_fp8((int)uw0[q], false);
            f32x2 h0 = __builtin_amdgcn_cvt_pk_f32_fp8((int)uw0[q], true);
            acc[q * 4 + 0] += w0 * l0.x;
            acc[q * 4 + 1] += w0 * l0.y;
            acc[q * 4 + 2] += w0 * h0.x;
            acc[q * 4 + 3] += w0 * h0.y;
        }
    }
    float di = dinv[node], di2 = di * di;
    uint4 us = ((const uint4*)(t + (size_t)node * 1024))[lane];
    const unsigned int uws[4] = {us.x, us.y, us.z, us.w};
    Pack8 o0, o1;
#pragma unroll
    for (int q = 0; q < 4; ++q) {
        f32x2 sl = __builtin_amdgcn_cvt_pk_f32_fp8((int)uws[q], false);
        f32x2 sh = __builtin_amdgcn_cvt_pk_f32_fp8((int)uws[q], true);
        float4 b = *(const float4*)(bias + 16 * lane + q * 4);
        float v0 = di * acc[q * 4 + 0] + di2 * sl.x + b.x;
        float v1 = di * acc[q * 4 + 1] + di2 * sl.y + b.y;
        float v2 = di * acc[q * 4 + 2] + di2 * sh.x + b.z;
        float v3 = di * acc[q * 4 + 3] + di2 * sh.y + b.w;
        if (RELU) {
            v0 = fmaxf(v0, 0.f); v1 = fmaxf(v1, 0.f);
            v2 = fmaxf(v2, 0.f); v3 = fmaxf(v3, 0.f);
        }
        Pack8& dst8 = (q < 2) ? o0 : o1;
        int base = (q & 1) * 4;
        dst8.h[base + 0] = (f16)v0;
        dst8.h[base + 1] = (f16)v1;
        dst8.h[base + 2] = (f16)v2;
        dst8.h[base + 3] = (f16)v3;
    }
    uint4* orow = (uint4*)(out + (size_t)node * 1024 + 16 * lane);
    orow[0] = o0.v;
    orow[1] = o1.v;
}

// ---------------------------------------------------------------------------
// fp8 aggregation over a 256-col tensor (layer 3): 64 lanes/node, one uint
// (4 fp8 cols) per lane per edge. Round-8-proven structure.
// ---------------------------------------------------------------------------
template <bool RELU>
__global__ __launch_bounds__(256) void agg_fp8_256(const unsigned char* __restrict__ t,
                                                   int in_ld,
                                                   const float* __restrict__ dinv,
                                                   const int* __restrict__ rs,
                                                   const int* __restrict__ csr,
                                                   const float* __restrict__ bias,
                                                   f16* __restrict__ out,
                                                   int out_ld, int nNodes) {
    int node = blockIdx.x * 4 + ((int)threadIdx.x >> 6);
    if (node >= nNodes) return;
    int lane = (int)threadIdx.x & 63;

    float acc0 = 0.f, acc1 = 0.f, acc2 = 0.f, acc3 = 0.f;
    int e0 = rs[node], e1 = rs[node + 1];
    int e = e0;
    for (; e + 1 < e1; e += 2) {
        int s0 = csr[e], s1 = csr[e + 1];
        float w0 = dinv[s0], w1 = dinv[s1];
        unsigned int u0 = ((const unsigned int*)(t + (size_t)s0 * in_ld))[lane];
        unsigned int u1 = ((const unsigned int*)(t + (size_t)s1 * in_ld))[lane];
        f32x2 l0 = __builtin_amdgcn_cvt_pk_f32_fp8((int)u0, false);
        f32x2 h0 = __builtin_amdgcn_cvt_pk_f32_fp8((int)u0, true);
        f32x2 l1 = __builtin_amdgcn_cvt_pk_f32_fp8((int)u1, false);
        f32x2 h1 = __builtin_amdgcn_cvt_pk_f32_fp8((int)u1, true);
        acc0 += w0 * l0.x + w1 * l1.x;
        acc1 += w0 * l0.y + w1 * l1.y;
        acc2 += w0 * h0.x + w1 * h1.x;
        acc3 += w0 * h0.y + w1 * h1.y;
    }
    if (e < e1) {
        int s0 = csr[e];
        float w0 = dinv[s0];
        unsigned int u0 = ((const unsigned int*)(t + (size_t)s0 * in_ld))[lane];
        f32x2 l0 = __builtin_amdgcn_cvt_pk_f32_fp8((int)u0, false);
        f32x2 h0 = __builtin_amdgcn_cvt_pk_f32_fp8((int)u0, true);
        acc0 += w0 * l0.x;
        acc1 += w0 * l0.y;
        acc2 += w0 * h0.x;
        acc3 += w0 * h0.y;
    }
    float di = dinv[node], di2 = di * di;
    unsigned int us = ((const unsigned int*)(t + (size_t)node * in_ld))[lane];
    f32x2 sl = __builtin_amdgcn_cvt_pk_f32_fp8((int)us, false);
    f32x2 sh = __builtin_amdgcn_cvt_pk_f32_fp8((int)us, true);
    float4 b = *(const float4*)(bias + 4 * lane);
    float v0 = di * acc0 + di2 * sl.x + b.x;
    float v1 = di * acc1 + di2 * sl.y + b.y;
    float v2 = di * acc2 + di2 * sh.x + b.z;
    float v3 = di * acc3 + di2 * sh.y + b.w;
    if (RELU) {
        v0 = fmaxf(v0, 0.f); v1 = fmaxf(v1, 0.f);
        v2 = fmaxf(v2, 0.f); v3 = fmaxf(v3, 0.f);
    }
    Pack4 pk;
    pk.h[0] = (f16)v0; pk.h[1] = (f16)v1; pk.h[2] = (f16)v2; pk.h[3] = (f16)v3;
    *(uint2*)(out + (size_t)node * out_ld + 4 * lane) = pk.v;
}

// ---------------------------------------------------------------------------
// MFMA GEMM kernels. LDS row stride 40 f16 = 80 B (16 B-aligned).
// Fragments: A[m=lane&15][k=(lane>>4)*8+j]; B^T rows; C/D col=lane&15,
// row=(lane>>4)*4+reg.
// ---------------------------------------------------------------------------
#define LDSTR 40

// Fused layer1+2 (mfma10, measured 735/734 us in r8/r11 — BEST).
// Double-buffered LDSTR-40 LDS, ONE barrier per K-step, B one-K-step-ahead
// register prefetch. 2-phase exploration closed (rounds 1-10): {fewer
// barriers, conflict-free LDS, DMA staging, tile geometry} all tested;
// ~735 us is this structure's ceiling.
__global__ __launch_bounds__(512, 4) void gemm12_mfma10(const float* __restrict__ aggx,
                                                        const float* __restrict__ w1p,
                                                        const f16* __restrict__ Bt,
                                                        unsigned char* __restrict__ t2) {
    __shared__ f16 As[2 * 128 * LDSTR] __attribute__((aligned(16)));
    __shared__ f16 Bs[2 * 256 * LDSTR] __attribute__((aligned(16)));
    int tid = threadIdx.x;
    int m0  = blockIdx.x * 128;
    int n0c = blockIdx.y * 256;  // column chunk base in W2

    // A-recompute: 2 m-rows x 4 k per thread (64 row-pairs x 8 k-groups)
    int mg = tid >> 3;   // 0..63 -> rows 2mg, 2mg+1
    int kg = tid & 7;    // k group: kg*4 .. kg*4+3
    float a0[2], a1[2], a2[2];
#pragma unroll
    for (int j = 0; j < 2; ++j) {
        int gm = m0 + mg * 2 + j;
        if (gm < NN) {
            a0[j] = aggx[gm * 3 + 0];
            a1[j] = aggx[gm * 3 + 1];
            a2[j] = aggx[gm * 3 + 2];
        } else {
            a0[j] = a1[j] = a2[j] = 0.f;
        }
    }

    // B staging: 2 threads per n-row, 16 f16 each
    int brow = tid >> 1;            // 0..255
    int bkof = (tid & 1) * 16;
    const f16* bbase = Bt + (size_t)(n0c + brow) * 4096 + bkof;

    int lane   = tid & 63;
    int wv     = tid >> 6;          // 0..7
    int wm     = (wv >> 2) * 64;    // 0 or 64
    int wn     = (wv & 3) * 64;     // 0,64,128,192
    int fr_m   = lane & 15;
    int khalf8 = (lane >> 4) * 8;

    // A-stage helper (r0 body, parameterized destination buffer + k)
    auto stageA = [&](f16* dstAs, int kk) {
        int kb = kk + kg * 4;
        float4 wk0 = *(const float4*)(w1p + (size_t)(kb + 0) * 4);
        float4 wk1 = *(const float4*)(w1p + (size_t)(kb + 1) * 4);
        float4 wk2 = *(const float4*)(w1p + (size_t)(kb + 2) * 4);
        float4 wk3 = *(const float4*)(w1p + (size_t)(kb + 3) * 4);
#pragma unroll
        for (int j = 0; j < 2; ++j) {
            float h0 = fmaxf(a0[j] * wk0.x + a1[j] * wk0.y + a2[j] * wk0.z + wk0.w, 0.f);
            float h1 = fmaxf(a0[j] * wk1.x + a1[j] * wk1.y + a2[j] * wk1.z + wk1.w, 0.f);
            float h2 = fmaxf(a0[j] * wk2.x + a1[j] * wk2.y + a2[j] * wk2.z + wk2.w, 0.f);
            float h3 = fmaxf(a0[j] * wk3.x + a1[j] * wk3.y + a2[j] * wk3.z + wk3.w, 0.f);
            Pack4 pk;
            pk.h[0] = (f16)h0; pk.h[1] = (f16)h1; pk.h[2] = (f16)h2; pk.h[3] = (f16)h3;
            *(uint2*)(&dstAs[(mg * 2 + j) * LDSTR + kg * 4]) = pk.v;
        }
    };

    // ---- prologue: stage buffer 0 with k=0; load B regs for k=32 ----
    h8 pb0 = *(const h8*)(bbase);
    h8 pb1 = *(const h8*)(bbase + 8);
    stageA(As, 0);
    *(h8*)(&Bs[brow * LDSTR + bkof]) = pb0;
    *(h8*)(&Bs[brow * LDSTR + bkof + 8]) = pb1;
    pb0 = *(const h8*)(bbase + 32);
    pb1 = *(const h8*)(bbase + 32 + 8);

    f32x4 acc[4][4];
#pragma unroll
    for (int i = 0; i < 4; ++i)
#pragma unroll
        for (int j = 0; j < 4; ++j) acc[i][j] = (f32x4){0.f, 0.f, 0.f, 0.f};

    int p = 0;
    for (int k0 = 0; k0 < 4096; k0 += 32) {
        __syncthreads();  // buf[p] fully staged; all reads of buf[p^1] done
        const f16* Asc = As + p * (128 * LDSTR);
        const f16* Bsc = Bs + p * (256 * LDSTR);
        f16* Asn = As + (p ^ 1) * (128 * LDSTR);
        f16* Bsn = Bs + (p ^ 1) * (256 * LDSTR);

        // ---- stage NEXT K-tile into buf[p^1] (overlaps other waves' MFMA) ----
        int k1 = k0 + 32;
        if (k1 < 4096) {
            *(h8*)(&Bsn[brow * LDSTR + bkof]) = pb0;
            *(h8*)(&Bsn[brow * LDSTR + bkof + 8]) = pb1;
            stageA(Asn, k1);
        }

        // ---- frag reads from current buffer ----
        h8 af[4];
#pragma unroll
        for (int mt = 0; mt < 4; ++mt)
            af[mt] = *(const h8*)(&Asc[(wm + mt * 16 + fr_m) * LDSTR + khalf8]);

        // ---- prefetch B for k+64 (drains under MFMA phase) ----
        int k2 = k0 + 64;
        if (k2 < 4096) {
            pb0 = *(const h8*)(bbase + k2);
            pb1 = *(const h8*)(bbase + k2 + 8);
        }

#pragma unroll
        for (int nt = 0; nt < 4; ++nt) {
            h8 bf = *(const h8*)(&Bsc[(wn + nt * 16 + fr_m) * LDSTR + khalf8]);
#pragma unroll
            for (int mt = 0; mt < 4; ++mt)
                acc[mt][nt] = __builtin_amdgcn_mfma_f32_16x16x32_f16(af[mt], bf, acc[mt][nt], 0, 0, 0);
        }
        p ^= 1;
    }

#pragma unroll
    for (int mt = 0; mt < 4; ++mt) {
#pragma unroll
        for (int reg = 0; reg < 4; ++reg) {
            int gm = m0 + wm + mt * 16 + (lane >> 4) * 4 + reg;
            if (gm < NN) {
                unsigned char* orow = t2 + (size_t)gm * 1024 + n0c + wn + fr_m;
#pragma unroll
                for (int nt = 0; nt < 4; ++nt)
                    orow[nt * 16] = f2fp8(acc[mt][nt][reg]);
            }
        }
    }
}

// Generic MFMA GEMM (layer 3): C(fp8)[M,ldc] = A[M,lda](f16) @ Bt[N][K](f16)^T
// 128x128 tile, register-prefetched staging. 20.5 KB LDS -> 8 blocks/CU.
__global__ __launch_bounds__(256) void gemm_mfma(const f16* __restrict__ A, int lda,
                                                 const f16* __restrict__ Bt, int K,
                                                 unsigned char* __restrict__ C, int ldc,
                                                 int M) {
    __shared__ f16 As[128 * LDSTR] __attribute__((aligned(16)));
    __shared__ f16 Bs[128 * LDSTR] __attribute__((aligned(16)));
    int tid = threadIdx.x;
    int m0 = blockIdx.y * 128;
    int n0 = blockIdx.x * 128;

    int row = tid >> 1;
    int kof = (tid & 1) * 16;
    int am  = m0 + row;
    if (am > M - 1) am = M - 1;

    int lane   = tid & 63;
    int wv     = tid >> 6;
    int fr_m   = lane & 15;
    int khalf8 = (lane >> 4) * 8;

    const f16* abase = A + (size_t)am * lda + kof;
    const f16* bbase = Bt + (size_t)(n0 + row) * K + kof;

    h8 pa0 = *(const h8*)(abase);
    h8 pa1 = *(const h8*)(abase + 8);
    h8 pb0 = *(const h8*)(bbase);
    h8 pb1 = *(const h8*)(bbase + 8);

    f32x4 acc[2][8];
#pragma unroll
    for (int i = 0; i < 2; ++i)
#pragma unroll
        for (int j = 0; j < 8; ++j) acc[i][j] = (f32x4){0.f, 0.f, 0.f, 0.f};

    for (int k0 = 0; k0 < K; k0 += 32) {
        *(h8*)(&As[row * LDSTR + kof]) = pa0;
        *(h8*)(&As[row * LDSTR + kof + 8]) = pa1;
        *(h8*)(&Bs[row * LDSTR + kof]) = pb0;
        *(h8*)(&Bs[row * LDSTR + kof + 8]) = pb1;
        __syncthreads();

        int kn = k0 + 32;
        if (kn < K) {
            pa0 = *(const h8*)(abase + kn);
            pa1 = *(const h8*)(abase + kn + 8);
            pb0 = *(const h8*)(bbase + kn);
            pb1 = *(const h8*)(bbase + kn + 8);
        }

        h8 af0 = *(const h8*)(&As[(wv * 32 + fr_m) * LDSTR + khalf8]);
        h8 af1 = *(const h8*)(&As[(wv * 32 + 16 + fr_m) * LDSTR + khalf8]);
#pragma unroll
        for (int nt = 0; nt < 8; ++nt) {
            h8 bf = *(const h8*)(&Bs[(nt * 16 + fr_m) * LDSTR + khalf8]);
            acc[0][nt] = __builtin_amdgcn_mfma_f32_16x16x32_f16(af0, bf, acc[0][nt], 0, 0, 0);
            acc[1][nt] = __builtin_amdgcn_mfma_f32_16x16x32_f16(af1, bf, acc[1][nt], 0, 0, 0);
        }
        __syncthreads();
    }

#pragma unroll
    for (int mt = 0; mt < 2; ++mt) {
#pragma unroll
        for (int reg = 0; reg < 4; ++reg) {
            int gm = m0 + wv * 32 + mt * 16 + (lane >> 4) * 4 + reg;
            if (gm < M) {
                unsigned char* orow = C + (size_t)gm * ldc + n0 + fr_m;
#pragma unroll
                for (int nt = 0; nt < 8; ++nt)
                    orow[nt * 16] = f2fp8(acc[mt][nt][reg]);
            }
        }
    }
}

// ---------------------------------------------------------------------------
// Layer-4 GEMM: C[M,64] f16 = A[M,256](f16) @ B[256,64](f32)
// f16 output halves t4 write + halves agg<64>'s 256 B/edge gather.
// ---------------------------------------------------------------------------
#define BM 64
#define BN 64
#define BKS 16
__global__ __launch_bounds__(256) void gemm_f16A_kernel(const f16* __restrict__ A,
                                                        const float* __restrict__ B,
                                                        f16* __restrict__ C,
                                                        int M, int K, int N) {
    __shared__ float As[BKS][BM + 4];
    __shared__ float Bs[BKS][BN + 4];
    int tid = threadIdx.x;
    int tx = tid & 15;
    int ty = tid >> 4;
    int m0 = blockIdx.y * BM;
    int n0 = blockIdx.x * BN;

    float acc[4][4];
#pragma unroll
    for (int i = 0; i < 4; ++i)
#pragma unroll
        for (int j = 0; j < 4; ++j) acc[i][j] = 0.f;

    int lmA = tid >> 2;
    int lkA = (tid & 3) * 4;
    int lkB = tid >> 4;
    int lnB = (tid & 15) * 4;

    for (int k0 = 0; k0 < K; k0 += BKS) {
        int gm = m0 + lmA;
        if (gm > M - 1) gm = M - 1;
        h4v av = *(const h4v*)(A + (size_t)gm * K + k0 + lkA);
        As[lkA + 0][lmA] = (float)av.x;
        As[lkA + 1][lmA] = (float)av.y;
        As[lkA + 2][lmA] = (float)av.z;
        As[lkA + 3][lmA] = (float)av.w;
        float4 bv = *reinterpret_cast<const float4*>(B + (size_t)(k0 + lkB) * N + n0 + lnB);
        *reinterpret_cast<float4*>(&Bs[lkB][lnB]) = bv;
        __syncthreads();

#pragma unroll
        for (int k = 0; k < BKS; ++k) {
            float4 a4 = *reinterpret_cast<const float4*>(&As[k][ty * 4]);
            float4 b4 = *reinterpret_cast<const float4*>(&Bs[k][tx * 4]);
            float a[4] = {a4.x, a4.y, a4.z, a4.w};
            float b[4] = {b4.x, b4.y, b4.z, b4.w};
#pragma unroll
            for (int i = 0; i < 4; ++i)
#pragma unroll
                for (int j = 0; j < 4; ++j) acc[i][j] += a[i] * b[j];
        }
        __syncthreads();
    }

#pragma unroll
    for (int i = 0; i < 4; ++i) {
        int m = m0 + ty * 4 + i;
        if (m < M) {
            Pack4 pk;
            pk.h[0] = (f16)acc[i][0]; pk.h[1] = (f16)acc[i][1];
            pk.h[2] = (f16)acc[i][2]; pk.h[3] = (f16)acc[i][3];
            *reinterpret_cast<uint2*>(C + (size_t)m * N + n0 + tx * 4) = pk.v;
        }
    }
}

// Layer-5 GEMM: t5(f16) = h4[NN,64](f16) @ W5[64,16](f32)
__global__ __launch_bounds__(256) void gemm5_kernel(const f16* __restrict__ h4,
                                                    const float* __restrict__ W5,
                                                    f16* __restrict__ t5, int nNodes) {
    int idx = blockIdx.x * 256 + threadIdx.x;
    int i = idx >> 4, j = idx & 15;
    if (i >= nNodes) return;
    const f16* a = h4 + (size_t)i * 64;
    float s = 0.f;
#pragma unroll
    for (int k = 0; k < 64; ++k) s += (float)a[k] * W5[k * 16 + j];
    t5[idx] = (f16)s;
}

// Pool + classifier
__global__ __launch_bounds__(256) void pool_kernel(const float* __restrict__ h5,
                                                   float* __restrict__ pool) {
    __shared__ float red[256];
    int c = blockIdx.x;
    float s = 0.f;
    for (int i = threadIdx.x; i < NN; i += 256) s += h5[(size_t)i * 16 + c];
    red[threadIdx.x] = s;
    __syncthreads();
    for (int off = 128; off > 0; off >>= 1) {
        if ((int)threadIdx.x < off) red[threadIdx.x] += red[threadIdx.x + off];
        __syncthreads();
    }
    if (threadIdx.x == 0) pool[c] = red[0];
}

__global__ void final_kernel(const float* __restrict__ pool, const float* __restrict__ Wl,
                             const float* __restrict__ bl, float* __restrict__ out) {
    int j = threadIdx.x;
    if (j < 3) {
        float s = 0.f;
#pragma unroll
        for (int c = 0; c < 16; ++c) s += pool[c] * Wl[c * 3 + j];
        out[j] = s * (1.0f / (float)NN) + bl[j];
    }
}

// ---------------------------------------------------------------------------
// Host launcher — workspace ledger ~205 MB (csr restored; t4/t5 are f16
// views of tbuf).
// ---------------------------------------------------------------------------
extern "C" void kernel_launch(void* const* d_in, const int* in_sizes, int n_in,
                              void* d_out, int out_size, void* d_ws, size_t ws_size,
                              hipStream_t stream) {
    (void)in_sizes; (void)n_in; (void)out_size; (void)ws_size;

    const float* x  = (const float*)d_in[0];
    const int*   ei = (const int*)d_in[1];
    const float* W1 = (const float*)d_in[2];
    const float* b1 = (const float*)d_in[3];
    const float* W2 = (const float*)d_in[4];
    const float* b2 = (const float*)d_in[5];
    const float* W3 = (const float*)d_in[6];
    const float* b3 = (const float*)d_in[7];
    const float* W4 = (const float*)d_in[8];
    const float* b4 = (const float*)d_in[9];
    const float* W5 = (const float*)d_in[10];
    const float* b5 = (const float*)d_in[11];
    const float* Wl = (const float*)d_in[12];
    const float* bl = (const float*)d_in[13];
    float* out = (float*)d_out;

    const int* srcp = ei;
    const int* dstp = ei + NE;

    char* p = (char*)d_ws;
    auto carve = [&](size_t bytes) {
        char* r = p;
        p += (bytes + 255) & ~(size_t)255;
        return r;
    };
    int*   deg  = (int*)carve(NN * 4);
    int*   cur  = (int*)carve(NN * 4);
    int*   rs   = (int*)carve((NN + 1) * 4);
    int*   bsum = (int*)carve(256 * 4);
    int*   csr  = (int*)carve((size_t)NE * 4);
    float* dinv = (float*)carve(NN * 4);
    float* aggx = (float*)carve((size_t)NN * 3 * 4);
    float* pool = (float*)carve(16 * 4);
    float* w1p  = (float*)carve((size_t)4096 * 4 * 4);       // 64 KB
    f16*   w2t  = (f16*)carve((size_t)1024 * 4096 * 2);      // 8.4 MB
    f16*   w3t  = (f16*)carve((size_t)256 * 1024 * 2);       // 0.5 MB
    unsigned char* tbuf = (unsigned char*)carve((size_t)NN * 1024);  // 51.2 MB: fp8 t2/t3, f16 t4/t5 view
    f16*   h2   = (f16*)carve((size_t)NN * 1024 * 2);        // 102.4 MB
    f16*   h3   = (f16*)carve((size_t)NN * 256 * 2);         // 25.6 MB
    f16*   h4   = (f16*)carve((size_t)NN * 64 * 2);          // 6.4 MB
    float* h5   = (float*)carve((size_t)NN * 16 * 4);        // 3.2 MB
    f16*   tf16 = (f16*)tbuf;                                // f16 view for t4/t5

    const int NB = (NN + 255) / 256;  // 196

    zero_int_kernel<<<NB, 256, 0, stream>>>(deg, NN);
    zero_int_kernel<<<NB, 256, 0, stream>>>(cur, NN);
    count_kernel<<<(NE + 255) / 256, 256, 0, stream>>>(dstp, deg, NE);
    dinv_kernel<<<NB, 256, 0, stream>>>(deg, dinv, NN);
    scan1_kernel<<<NB, 256, 0, stream>>>(deg, rs, bsum, NN);
    scan2_kernel<<<1, 256, 0, stream>>>(bsum, rs, NB, NN);
    scan3_kernel<<<NB, 256, 0, stream>>>(rs, bsum, NN);
    fill_kernel<<<(NE + 255) / 256, 256, 0, stream>>>(srcp, dstp, rs, cur, csr, NE);

    // Weight prep
    pack_w1_kernel<<<16, 256, 0, stream>>>(W1, b1, w1p);
    tconv_kernel<<<dim3(1024 / 32, 4096 / 32), 256, 0, stream>>>(W2, w2t, 4096, 1024);
    tconv_kernel<<<dim3(256 / 32, 1024 / 32), 256, 0, stream>>>(W3, w3t, 1024, 256);

    // aggx = A_hat @ x (width 3, fp32)
    agg_kernel<3, 1, false, false, float, float><<<NB, 256, 0, stream>>>(
        x, dinv, rs, csr, nullptr, aggx, 3, NN);

    const int MB2 = (NN + 127) / 128;  // 391

    // Layers 1+2 fused: one 512-thread MFMA launch for all 1024 cols (fp8 out)
    gemm12_mfma10<<<dim3(MB2, 4), 512, 0, stream>>>(aggx, w1p, w2t, tbuf);
    // h2 = relu(A_hat t2 + b2): ONE pass, uint4/lane (16 B) per edge
    agg_fp8_1024<true><<<(NN + 3) / 4, 256, 0, stream>>>(
        tbuf, dinv, rs, csr, b2, h2, NN);

    // Layer 3 (MFMA, fp8 out): t3 = h2 @ W3; h3 = relu(A_hat t3 + b3)
    gemm_mfma<<<dim3(2, MB2), 256, 0, stream>>>(
        h2, 1024, w3t, 1024, tbuf, 256, NN);
    agg_fp8_256<true><<<(NN + 3) / 4, 256, 0, stream>>>(
        tbuf, 256, dinv, rs, csr, b3, h3, 256, NN);

    // Layer 4: t4(f16) = h3 @ W4 [NN,64]; h4 = relu(A_hat t4 + b4) -> f16
    gemm_f16A_kernel<<<dim3(1, (NN + BM - 1) / BM), 256, 0, stream>>>(
        h3, W4, tf16, NN, 256, 64);
    agg_kernel<64, 64, true, true, f16, f16><<<(NN + 3) / 4, 256, 0, stream>>>(
        tf16, dinv, rs, csr, b4, h4, 64, NN);

    // Layer 5: t5(f16) = h4 @ W5 [NN,16]; h5 = A_hat t5 + b5 (no relu, f32)
    gemm5_kernel<<<(NN * 16 + 255) / 256, 256, 0, stream>>>(h4, W5, tf16, NN);
    agg_kernel<16, 16, false, true, f16, float><<<(NN + 15) / 16, 256, 0, stream>>>(
        tf16, dinv, rs, csr, b5, h5, 16, NN);

    // Global mean pool + classifier
    pool_kernel<<<16, 256, 0, stream>>>(h5, pool);
    final_kernel<<<1, 64, 0, stream>>>(pool, Wl, bl, out);
}

// Round 13
// 1560.777 us; speedup vs baseline: 1.1655x; 1.0058x over previous
//
#include <hip/hip_runtime.h>
#include <stdint.h>

#define NN 50000
#define NE 1600000

typedef _Float16 f16;
typedef __attribute__((ext_vector_type(8))) _Float16 h8;
typedef __attribute__((ext_vector_type(4))) _Float16 h4v;
typedef __attribute__((ext_vector_type(4))) float f32x4;
typedef __attribute__((ext_vector_type(2))) float f32x2;

union PackU { unsigned int u; f16 h[2]; };
union Pack4 { uint2 v; f16 h[4]; };
union Pack8 { uint4 v; f16 h[8]; };

__device__ __forceinline__ void storev(float* p, float v) { *p = v; }
__device__ __forceinline__ void storev(f16* p, float v) { *p = (f16)v; }

__device__ __forceinline__ unsigned char f2fp8(float v) {
    int pk = __builtin_amdgcn_cvt_pk_fp8_f32(v, v, 0, false);
    return (unsigned char)(pk & 0xff);
}

// ---------------------------------------------------------------------------
// Preprocessing
// ---------------------------------------------------------------------------
__global__ __launch_bounds__(256) void zero_int_kernel(int* __restrict__ p, int n) {
    int i = blockIdx.x * 256 + threadIdx.x;
    if (i < n) p[i] = 0;
}

__global__ __launch_bounds__(256) void count_kernel(const int* __restrict__ dst,
                                                    int* __restrict__ deg, int nE) {
    int e = blockIdx.x * 256 + threadIdx.x;
    if (e < nE) atomicAdd(&deg[dst[e]], 1);
}

__global__ __launch_bounds__(256) void dinv_kernel(const int* __restrict__ deg,
                                                   float* __restrict__ dinv, int n) {
    int i = blockIdx.x * 256 + threadIdx.x;
    if (i < n) dinv[i] = rsqrtf((float)deg[i] + 1.0f);
}

// Parallel 3-phase exclusive scan over 50000 ints (196 blocks of 256).
__global__ __launch_bounds__(256) void scan1_kernel(const int* __restrict__ cnt,
                                                    int* __restrict__ rs,
                                                    int* __restrict__ bsum, int n) {
    __shared__ int sm[256];
    int b = blockIdx.x, t = threadIdx.x, i = b * 256 + t;
    int v = (i < n) ? cnt[i] : 0;
    sm[t] = v;
    __syncthreads();
    for (int off = 1; off < 256; off <<= 1) {
        int x = 0;
        if (t >= off) x = sm[t - off];
        __syncthreads();
        if (t >= off) sm[t] += x;
        __syncthreads();
    }
    if (i < n) rs[i] = sm[t] - v;  // block-local exclusive
    if (t == 255) bsum[b] = sm[255];
}

__global__ __launch_bounds__(256) void scan2_kernel(int* __restrict__ bsum,
                                                    int* __restrict__ rs, int nb, int n) {
    __shared__ int sm[256];
    int t = threadIdx.x;
    int v = (t < nb) ? bsum[t] : 0;
    sm[t] = v;
    __syncthreads();
    for (int off = 1; off < 256; off <<= 1) {
        int x = 0;
        if (t >= off) x = sm[t - off];
        __syncthreads();
        if (t >= off) sm[t] += x;
        __syncthreads();
    }
    if (t < nb) bsum[t] = sm[t] - v;  // exclusive block offsets
    if (t == 255) rs[n] = sm[255];    // grand total (= nE)
}

__global__ __launch_bounds__(256) void scan3_kernel(int* __restrict__ rs,
                                                    const int* __restrict__ bsum, int n) {
    int i = blockIdx.x * 256 + threadIdx.x;
    if (i < n) rs[i] += bsum[blockIdx.x];
}

__global__ __launch_bounds__(256) void fill_kernel(const int* __restrict__ src,
                                                   const int* __restrict__ dst,
                                                   const int* __restrict__ rs,
                                                   int* __restrict__ cur,
                                                   int* __restrict__ csr, int nE) {
    int e = blockIdx.x * 256 + threadIdx.x;
    if (e < nE) {
        int d = dst[e];
        int p = rs[d] + atomicAdd(&cur[d], 1);
        csr[p] = src[e];
    }
}

// w1p[k*4 + {0,1,2,3}] = {W1[0][k], W1[1][k], W1[2][k], b1[k]}
__global__ __launch_bounds__(256) void pack_w1_kernel(const float* __restrict__ W1,
                                                      const float* __restrict__ b1,
                                                      float* __restrict__ w1p) {
    int k = blockIdx.x * 256 + threadIdx.x;
    if (k < 4096) {
        w1p[k * 4 + 0] = W1[k];
        w1p[k * 4 + 1] = W1[4096 + k];
        w1p[k * 4 + 2] = W1[8192 + k];
        w1p[k * 4 + 3] = b1[k];
    }
}

// Transpose-convert: Wt[n][k] = f16(W[k][n]); K, N multiples of 32.
__global__ __launch_bounds__(256) void tconv_kernel(const float* __restrict__ W,
                                                    f16* __restrict__ Wt,
                                                    int K, int N) {
    __shared__ float tile[32][33];
    int kb = blockIdx.y * 32, nb = blockIdx.x * 32;
    int tx = threadIdx.x & 31, ty = threadIdx.x >> 5;
    for (int r = ty; r < 32; r += 8)
        tile[r][tx] = W[(size_t)(kb + r) * N + nb + tx];
    __syncthreads();
    for (int r = ty; r < 32; r += 8)
        Wt[(size_t)(nb + r) * K + kb + tx] = (f16)tile[tx][r];
}

// ---------------------------------------------------------------------------
// Input-typed aggregation (widths 3, 64, 16). InT = float or f16.
// TPN=3 path (aggx): 3 lanes/node -> 150K threads (2.3 waves/SIMD) vs the
// old TPN=1's 50K (0.77/SIMD) — fixes the latency-bound under-occupancy.
// Bit-exact: per-column edge summation order unchanged.
// ---------------------------------------------------------------------------
template <int F, int TPN, bool RELU, bool BIAS, typename InT, typename OutT>
__global__ __launch_bounds__(256) void agg_kernel(const InT* __restrict__ t,
                                                  const float* __restrict__ dinv,
                                                  const int* __restrict__ rs,
                                                  const int* __restrict__ csr,
                                                  const float* __restrict__ bias,
                                                  OutT* __restrict__ out, int out_ld,
                                                  int nNodes) {
    constexpr int NPB = 256 / TPN;
    constexpr int C   = F / TPN;
    static_assert(TPN * C == F, "F must be TPN*C");
    if ((int)threadIdx.x >= NPB * TPN) return;  // tail guard for TPN=3
    int node = blockIdx.x * NPB + (int)threadIdx.x / TPN;
    if (node >= nNodes) return;
    int lane = (int)threadIdx.x % TPN;

    float acc[C];
#pragma unroll
    for (int c = 0; c < C; ++c) acc[c] = 0.f;

    int e0 = rs[node], e1 = rs[node + 1];
    for (int e = e0; e < e1; ++e) {
        int s = csr[e];
        float w = dinv[s];
        const InT* tr = t + (size_t)s * F;
#pragma unroll
        for (int c = 0; c < C; ++c) acc[c] += w * (float)tr[lane + c * TPN];
    }
    float di = dinv[node];
    const InT* ti = t + (size_t)node * F;
    OutT* oi = out + (size_t)node * out_ld;
#pragma unroll
    for (int c = 0; c < C; ++c) {
        int col = lane + c * TPN;
        float v = di * acc[c] + di * di * (float)ti[col];
        if (BIAS) v += bias[col];
        if (RELU) v = fmaxf(v, 0.f);
        storev(oi + col, v);
    }
}

// ---------------------------------------------------------------------------
// fp8 aggregation, F=1024, SINGLE PASS: 64 lanes/node (4 nodes/block), each
// lane loads a uint4 (16 B = 16 fp8 cols) per edge -> one VMEM instruction
// covers the whole 1 KB row per wave.
// ---------------------------------------------------------------------------
template <bool RELU>
__global__ __launch_bounds__(256) void agg_fp8_1024(const unsigned char* __restrict__ t,
                                                    const float* __restrict__ dinv,
                                                    const int* __restrict__ rs,
                                                    const int* __restrict__ csr,
                                                    const float* __restrict__ bias,
                                                    f16* __restrict__ out, int nNodes) {
    int node = blockIdx.x * 4 + ((int)threadIdx.x >> 6);
    if (node >= nNodes) return;
    int lane = (int)threadIdx.x & 63;

    float acc[16];
#pragma unroll
    for (int j = 0; j < 16; ++j) acc[j] = 0.f;

    int e0 = rs[node], e1 = rs[node + 1];
    int e = e0;
    for (; e + 1 < e1; e += 2) {
        int s0 = csr[e], s1 = csr[e + 1];
        float w0 = dinv[s0], w1 = dinv[s1];
        uint4 u0 = ((const uint4*)(t + (size_t)s0 * 1024))[lane];
        uint4 u1 = ((const uint4*)(t + (size_t)s1 * 1024))[lane];
        const unsigned int uw0[4] = {u0.x, u0.y, u0.z, u0.w};
        const unsigned int uw1[4] = {u1.x, u1.y, u1.z, u1.w};
#pragma unroll
        for (int q = 0; q < 4; ++q) {
            f32x2 l0 = __builtin_amdgcn_cvt_pk_f32_fp8((int)uw0[q], false);
            f32x2 h0 = __builtin_amdgcn_cvt_pk_f32_fp8((int)uw0[q], true);
            f32x2 l1 = __builtin_amdgcn_cvt_pk_f32_fp8((int)uw1[q], false);
            f32x2 h1 = __builtin_amdgcn_cvt_pk_f32_fp8((int)uw1[q], true);
            acc[q * 4 + 0] += w0 * l0.x + w1 * l1.x;
            acc[q * 4 + 1] += w0 * l0.y + w1 * l1.y;
            acc[q * 4 + 2] += w0 * h0.x + w1 * h1.x;
            acc[q * 4 + 3] += w0 * h0.y + w1 * h1.y;
        }
    }
    if (e < e1) {
        int s0 = csr[e];
        float w0 = dinv[s0];
        uint4 u0 = ((const uint4*)(t + (size_t)s0 * 1024))[lane];
        const unsigned int uw0[4] = {u0.x, u0.y, u0.z, u0.w};
#pragma unroll
        for (int q = 0; q < 4; ++q) {
            f32x2 l0 = __builtin_amdgcn_cvt_pk_f32_fp8((int)uw0[q], false);
            f32x2 h0 = __builtin_amdgcn_cvt_pk_f32_fp8((int)uw0[q], true);
            acc[q * 4 + 0] += w0 * l0.x;
            acc[q * 4 + 1] += w0 * l0.y;
            acc[q * 4 + 2] += w0 * h0.x;
            acc[q * 4 + 3] += w0 * h0.y;
        }
    }
    float di = dinv[node], di2 = di * di;
    uint4 us = ((const uint4*)(t + (size_t)node * 1024))[lane];
    const unsigned int uws[4] = {us.x, us.y, us.z, us.w};
    Pack8 o0, o1;
#pragma unroll
    for (int q = 0; q < 4; ++q) {
        f32x2 sl = __builtin_amdgcn_cvt_pk_f32_fp8((int)uws[q], false);
        f32x2 sh = __builtin_amdgcn_cvt_pk_f32_fp8((int)uws[q], true);
        float4 b = *(const float4*)(bias + 16 * lane + q * 4);
        float v0 = di * acc[q * 4 + 0] + di2 * sl.x + b.x;
        float v1 = di * acc[q * 4 + 1] + di2 * sl.y + b.y;
        float v2 = di * acc[q * 4 + 2] + di2 * sh.x + b.z;
        float v3 = di * acc[q * 4 + 3] + di2 * sh.y + b.w;
        if (RELU) {
            v0 = fmaxf(v0, 0.f); v1 = fmaxf(v1, 0.f);
            v2 = fmaxf(v2, 0.f); v3 = fmaxf(v3, 0.f);
        }
        Pack8& dst8 = (q < 2) ? o0 : o1;
        int base = (q & 1) * 4;
        dst8.h[base + 0] = (f16)v0;
        dst8.h[base + 1] = (f16)v1;
        dst8.h[base + 2] = (f16)v2;
        dst8.h[base + 3] = (f16)v3;
    }
    uint4* orow = (uint4*)(out + (size_t)node * 1024 + 16 * lane);
    orow[0] = o0.v;
    orow[1] = o1.v;
}

// ---------------------------------------------------------------------------
// fp8 aggregation over a 256-col tensor (layer 3): 64 lanes/node, one uint
// (4 fp8 cols) per lane per edge. Round-8-proven structure.
// ---------------------------------------------------------------------------
template <bool RELU>
__global__ __launch_bounds__(256) void agg_fp8_256(const unsigned char* __restrict__ t,
                                                   int in_ld,
                                                   const float* __restrict__ dinv,
                                                   const int* __restrict__ rs,
                                                   const int* __restrict__ csr,
                                                   const float* __restrict__ bias,
                                                   f16* __restrict__ out,
                                                   int out_ld, int nNodes) {
    int node = blockIdx.x * 4 + ((int)threadIdx.x >> 6);
    if (node >= nNodes) return;
    int lane = (int)threadIdx.x & 63;

    float acc0 = 0.f, acc1 = 0.f, acc2 = 0.f, acc3 = 0.f;
    int e0 = rs[node], e1 = rs[node + 1];
    int e = e0;
    for (; e + 1 < e1; e += 2) {
        int s0 = csr[e], s1 = csr[e + 1];
        float w0 = dinv[s0], w1 = dinv[s1];
        unsigned int u0 = ((const unsigned int*)(t + (size_t)s0 * in_ld))[lane];
        unsigned int u1 = ((const unsigned int*)(t + (size_t)s1 * in_ld))[lane];
        f32x2 l0 = __builtin_amdgcn_cvt_pk_f32_fp8((int)u0, false);
        f32x2 h0 = __builtin_amdgcn_cvt_pk_f32_fp8((int)u0, true);
        f32x2 l1 = __builtin_amdgcn_cvt_pk_f32_fp8((int)u1, false);
        f32x2 h1 = __builtin_amdgcn_cvt_pk_f32_fp8((int)u1, true);
        acc0 += w0 * l0.x + w1 * l1.x;
        acc1 += w0 * l0.y + w1 * l1.y;
        acc2 += w0 * h0.x + w1 * h1.x;
        acc3 += w0 * h0.y + w1 * h1.y;
    }
    if (e < e1) {
        int s0 = csr[e];
        float w0 = dinv[s0];
        unsigned int u0 = ((const unsigned int*)(t + (size_t)s0 * in_ld))[lane];
        f32x2 l0 = __builtin_amdgcn_cvt_pk_f32_fp8((int)u0, false);
        f32x2 h0 = __builtin_amdgcn_cvt_pk_f32_fp8((int)u0, true);
        acc0 += w0 * l0.x;
        acc1 += w0 * l0.y;
        acc2 += w0 * h0.x;
        acc3 += w0 * h0.y;
    }
    float di = dinv[node], di2 = di * di;
    unsigned int us = ((const unsigned int*)(t + (size_t)node * in_ld))[lane];
    f32x2 sl = __builtin_amdgcn_cvt_pk_f32_fp8((int)us, false);
    f32x2 sh = __builtin_amdgcn_cvt_pk_f32_fp8((int)us, true);
    float4 b = *(const float4*)(bias + 4 * lane);
    float v0 = di * acc0 + di2 * sl.x + b.x;
    float v1 = di * acc1 + di2 * sl.y + b.y;
    float v2 = di * acc2 + di2 * sh.x + b.z;
    float v3 = di * acc3 + di2 * sh.y + b.w;
    if (RELU) {
        v0 = fmaxf(v0, 0.f); v1 = fmaxf(v1, 0.f);
        v2 = fmaxf(v2, 0.f); v3 = fmaxf(v3, 0.f);
    }
    Pack4 pk;
    pk.h[0] = (f16)v0; pk.h[1] = (f16)v1; pk.h[2] = (f16)v2; pk.h[3] = (f16)v3;
    *(uint2*)(out + (size_t)node * out_ld + 4 * lane) = pk.v;
}

// ---------------------------------------------------------------------------
// MFMA GEMM kernels. LDS row stride 40 f16 = 80 B (16 B-aligned).
// Fragments: A[m=lane&15][k=(lane>>4)*8+j]; B^T rows; C/D col=lane&15,
// row=(lane>>4)*4+reg.
// ---------------------------------------------------------------------------
#define LDSTR 40

// Fused layer1+2 (mfma10, measured 729-735 us r8/r11/r12 — BEST; frozen).
__global__ __launch_bounds__(512, 4) void gemm12_mfma10(const float* __restrict__ aggx,
                                                        const float* __restrict__ w1p,
                                                        const f16* __restrict__ Bt,
                                                        unsigned char* __restrict__ t2) {
    __shared__ f16 As[2 * 128 * LDSTR] __attribute__((aligned(16)));
    __shared__ f16 Bs[2 * 256 * LDSTR] __attribute__((aligned(16)));
    int tid = threadIdx.x;
    int m0  = blockIdx.x * 128;
    int n0c = blockIdx.y * 256;  // column chunk base in W2

    // A-recompute: 2 m-rows x 4 k per thread (64 row-pairs x 8 k-groups)
    int mg = tid >> 3;   // 0..63 -> rows 2mg, 2mg+1
    int kg = tid & 7;    // k group: kg*4 .. kg*4+3
    float a0[2], a1[2], a2[2];
#pragma unroll
    for (int j = 0; j < 2; ++j) {
        int gm = m0 + mg * 2 + j;
        if (gm < NN) {
            a0[j] = aggx[gm * 3 + 0];
            a1[j] = aggx[gm * 3 + 1];
            a2[j] = aggx[gm * 3 + 2];
        } else {
            a0[j] = a1[j] = a2[j] = 0.f;
        }
    }

    // B staging: 2 threads per n-row, 16 f16 each
    int brow = tid >> 1;            // 0..255
    int bkof = (tid & 1) * 16;
    const f16* bbase = Bt + (size_t)(n0c + brow) * 4096 + bkof;

    int lane   = tid & 63;
    int wv     = tid >> 6;          // 0..7
    int wm     = (wv >> 2) * 64;    // 0 or 64
    int wn     = (wv & 3) * 64;     // 0,64,128,192
    int fr_m   = lane & 15;
    int khalf8 = (lane >> 4) * 8;

    // A-stage helper (r0 body, parameterized destination buffer + k)
    auto stageA = [&](f16* dstAs, int kk) {
        int kb = kk + kg * 4;
        float4 wk0 = *(const float4*)(w1p + (size_t)(kb + 0) * 4);
        float4 wk1 = *(const float4*)(w1p + (size_t)(kb + 1) * 4);
        float4 wk2 = *(const float4*)(w1p + (size_t)(kb + 2) * 4);
        float4 wk3 = *(const float4*)(w1p + (size_t)(kb + 3) * 4);
#pragma unroll
        for (int j = 0; j < 2; ++j) {
            float h0 = fmaxf(a0[j] * wk0.x + a1[j] * wk0.y + a2[j] * wk0.z + wk0.w, 0.f);
            float h1 = fmaxf(a0[j] * wk1.x + a1[j] * wk1.y + a2[j] * wk1.z + wk1.w, 0.f);
            float h2 = fmaxf(a0[j] * wk2.x + a1[j] * wk2.y + a2[j] * wk2.z + wk2.w, 0.f);
            float h3 = fmaxf(a0[j] * wk3.x + a1[j] * wk3.y + a2[j] * wk3.z + wk3.w, 0.f);
            Pack4 pk;
            pk.h[0] = (f16)h0; pk.h[1] = (f16)h1; pk.h[2] = (f16)h2; pk.h[3] = (f16)h3;
            *(uint2*)(&dstAs[(mg * 2 + j) * LDSTR + kg * 4]) = pk.v;
        }
    };

    // ---- prologue: stage buffer 0 with k=0; load B regs for k=32 ----
    h8 pb0 = *(const h8*)(bbase);
    h8 pb1 = *(const h8*)(bbase + 8);
    stageA(As, 0);
    *(h8*)(&Bs[brow * LDSTR + bkof]) = pb0;
    *(h8*)(&Bs[brow * LDSTR + bkof + 8]) = pb1;
    pb0 = *(const h8*)(bbase + 32);
    pb1 = *(const h8*)(bbase + 32 + 8);

    f32x4 acc[4][4];
#pragma unroll
    for (int i = 0; i < 4; ++i)
#pragma unroll
        for (int j = 0; j < 4; ++j) acc[i][j] = (f32x4){0.f, 0.f, 0.f, 0.f};

    int p = 0;
    for (int k0 = 0; k0 < 4096; k0 += 32) {
        __syncthreads();  // buf[p] fully staged; all reads of buf[p^1] done
        const f16* Asc = As + p * (128 * LDSTR);
        const f16* Bsc = Bs + p * (256 * LDSTR);
        f16* Asn = As + (p ^ 1) * (128 * LDSTR);
        f16* Bsn = Bs + (p ^ 1) * (256 * LDSTR);

        // ---- stage NEXT K-tile into buf[p^1] (overlaps other waves' MFMA) ----
        int k1 = k0 + 32;
        if (k1 < 4096) {
            *(h8*)(&Bsn[brow * LDSTR + bkof]) = pb0;
            *(h8*)(&Bsn[brow * LDSTR + bkof + 8]) = pb1;
            stageA(Asn, k1);
        }

        // ---- frag reads from current buffer ----
        h8 af[4];
#pragma unroll
        for (int mt = 0; mt < 4; ++mt)
            af[mt] = *(const h8*)(&Asc[(wm + mt * 16 + fr_m) * LDSTR + khalf8]);

        // ---- prefetch B for k+64 (drains under MFMA phase) ----
        int k2 = k0 + 64;
        if (k2 < 4096) {
            pb0 = *(const h8*)(bbase + k2);
            pb1 = *(const h8*)(bbase + k2 + 8);
        }

#pragma unroll
        for (int nt = 0; nt < 4; ++nt) {
            h8 bf = *(const h8*)(&Bsc[(wn + nt * 16 + fr_m) * LDSTR + khalf8]);
#pragma unroll
            for (int mt = 0; mt < 4; ++mt)
                acc[mt][nt] = __builtin_amdgcn_mfma_f32_16x16x32_f16(af[mt], bf, acc[mt][nt], 0, 0, 0);
        }
        p ^= 1;
    }

#pragma unroll
    for (int mt = 0; mt < 4; ++mt) {
#pragma unroll
        for (int reg = 0; reg < 4; ++reg) {
            int gm = m0 + wm + mt * 16 + (lane >> 4) * 4 + reg;
            if (gm < NN) {
                unsigned char* orow = t2 + (size_t)gm * 1024 + n0c + wn + fr_m;
#pragma unroll
                for (int nt = 0; nt < 4; ++nt)
                    orow[nt * 16] = f2fp8(acc[mt][nt][reg]);
            }
        }
    }
}

// Generic MFMA GEMM (layer 3): C(fp8)[M,ldc] = A[M,lda](f16) @ Bt[N][K](f16)^T
// 128x128 tile, register-prefetched staging. 20.5 KB LDS -> 8 blocks/CU.
__global__ __launch_bounds__(256) void gemm_mfma(const f16* __restrict__ A, int lda,
                                                 const f16* __restrict__ Bt, int K,
                                                 unsigned char* __restrict__ C, int ldc,
                                                 int M) {
    __shared__ f16 As[128 * LDSTR] __attribute__((aligned(16)));
    __shared__ f16 Bs[128 * LDSTR] __attribute__((aligned(16)));
    int tid = threadIdx.x;
    int m0 = blockIdx.y * 128;
    int n0 = blockIdx.x * 128;

    int row = tid >> 1;
    int kof = (tid & 1) * 16;
    int am  = m0 + row;
    if (am > M - 1) am = M - 1;

    int lane   = tid & 63;
    int wv     = tid >> 6;
    int fr_m   = lane & 15;
    int khalf8 = (lane >> 4) * 8;

    const f16* abase = A + (size_t)am * lda + kof;
    const f16* bbase = Bt + (size_t)(n0 + row) * K + kof;

    h8 pa0 = *(const h8*)(abase);
    h8 pa1 = *(const h8*)(abase + 8);
    h8 pb0 = *(const h8*)(bbase);
    h8 pb1 = *(const h8*)(bbase + 8);

    f32x4 acc[2][8];
#pragma unroll
    for (int i = 0; i < 2; ++i)
#pragma unroll
        for (int j = 0; j < 8; ++j) acc[i][j] = (f32x4){0.f, 0.f, 0.f, 0.f};

    for (int k0 = 0; k0 < K; k0 += 32) {
        *(h8*)(&As[row * LDSTR + kof]) = pa0;
        *(h8*)(&As[row * LDSTR + kof + 8]) = pa1;
        *(h8*)(&Bs[row * LDSTR + kof]) = pb0;
        *(h8*)(&Bs[row * LDSTR + kof + 8]) = pb1;
        __syncthreads();

        int kn = k0 + 32;
        if (kn < K) {
            pa0 = *(const h8*)(abase + kn);
            pa1 = *(const h8*)(abase + kn + 8);
            pb0 = *(const h8*)(bbase + kn);
            pb1 = *(const h8*)(bbase + kn + 8);
        }

        h8 af0 = *(const h8*)(&As[(wv * 32 + fr_m) * LDSTR + khalf8]);
        h8 af1 = *(const h8*)(&As[(wv * 32 + 16 + fr_m) * LDSTR + khalf8]);
#pragma unroll
        for (int nt = 0; nt < 8; ++nt) {
            h8 bf = *(const h8*)(&Bs[(nt * 16 + fr_m) * LDSTR + khalf8]);
            acc[0][nt] = __builtin_amdgcn_mfma_f32_16x16x32_f16(af0, bf, acc[0][nt], 0, 0, 0);
            acc[1][nt] = __builtin_amdgcn_mfma_f32_16x16x32_f16(af1, bf, acc[1][nt], 0, 0, 0);
        }
        __syncthreads();
    }

#pragma unroll
    for (int mt = 0; mt < 2; ++mt) {
#pragma unroll
        for (int reg = 0; reg < 4; ++reg) {
            int gm = m0 + wv * 32 + mt * 16 + (lane >> 4) * 4 + reg;
            if (gm < M) {
                unsigned char* orow = C + (size_t)gm * ldc + n0 + fr_m;
#pragma unroll
                for (int nt = 0; nt < 8; ++nt)
                    orow[nt * 16] = f2fp8(acc[mt][nt][reg]);
            }
        }
    }
}

// ---------------------------------------------------------------------------
// Layer-4 MFMA GEMM: C(f16)[M,64] = A[M,256](f16) @ Bt[64][256](f16)^T.
// 128m x 64n tile, 4 waves (wave wv = rows wv*32..+31, all 64 cols).
// Same fragment pattern as gemm_mfma; 15.4 KB LDS. Replaces the VALU
// gemm_f16A (MFMA does 1.6 GFLOP in ~1/3 the time).
// ---------------------------------------------------------------------------
__global__ __launch_bounds__(256) void gemm_mfma_n64(const f16* __restrict__ A,
                                                     const f16* __restrict__ Bt,
                                                     f16* __restrict__ C, int M) {
    __shared__ f16 As[128 * LDSTR] __attribute__((aligned(16)));
    __shared__ f16 Bs[64 * LDSTR] __attribute__((aligned(16)));
    int tid = threadIdx.x;
    int m0 = blockIdx.x * 128;

    int row = tid >> 1;             // 0..127
    int kof = (tid & 1) * 16;
    int am  = m0 + row;
    if (am > M - 1) am = M - 1;

    int lane   = tid & 63;
    int wv     = tid >> 6;          // 0..3
    int fr_m   = lane & 15;
    int khalf8 = (lane >> 4) * 8;

    const f16* abase = A + (size_t)am * 256 + kof;
    // B staging: threads 0..127 stage 64 rows x 32 k
    int brow = (tid & 127) >> 1;    // 0..63
    const f16* bbase = Bt + (size_t)brow * 256 + kof;
    bool doB = tid < 128;

    h8 pa0 = *(const h8*)(abase);
    h8 pa1 = *(const h8*)(abase + 8);
    h8 pb0, pb1;
    if (doB) {
        pb0 = *(const h8*)(bbase);
        pb1 = *(const h8*)(bbase + 8);
    }

    f32x4 acc[2][4];
#pragma unroll
    for (int i = 0; i < 2; ++i)
#pragma unroll
        for (int j = 0; j < 4; ++j) acc[i][j] = (f32x4){0.f, 0.f, 0.f, 0.f};

    for (int k0 = 0; k0 < 256; k0 += 32) {
        *(h8*)(&As[row * LDSTR + kof]) = pa0;
        *(h8*)(&As[row * LDSTR + kof + 8]) = pa1;
        if (doB) {
            *(h8*)(&Bs[brow * LDSTR + kof]) = pb0;
            *(h8*)(&Bs[brow * LDSTR + kof + 8]) = pb1;
        }
        __syncthreads();

        int kn = k0 + 32;
        if (kn < 256) {
            pa0 = *(const h8*)(abase + kn);
            pa1 = *(const h8*)(abase + kn + 8);
            if (doB) {
                pb0 = *(const h8*)(bbase + kn);
                pb1 = *(const h8*)(bbase + kn + 8);
            }
        }

        h8 af0 = *(const h8*)(&As[(wv * 32 + fr_m) * LDSTR + khalf8]);
        h8 af1 = *(const h8*)(&As[(wv * 32 + 16 + fr_m) * LDSTR + khalf8]);
#pragma unroll
        for (int nt = 0; nt < 4; ++nt) {
            h8 bf = *(const h8*)(&Bs[(nt * 16 + fr_m) * LDSTR + khalf8]);
            acc[0][nt] = __builtin_amdgcn_mfma_f32_16x16x32_f16(af0, bf, acc[0][nt], 0, 0, 0);
            acc[1][nt] = __builtin_amdgcn_mfma_f32_16x16x32_f16(af1, bf, acc[1][nt], 0, 0, 0);
        }
        __syncthreads();
    }

#pragma unroll
    for (int mt = 0; mt < 2; ++mt) {
#pragma unroll
        for (int reg = 0; reg < 4; ++reg) {
            int gm = m0 + wv * 32 + mt * 16 + (lane >> 4) * 4 + reg;
            if (gm < M) {
                f16* orow = C + (size_t)gm * 64 + fr_m;
#pragma unroll
                for (int nt = 0; nt < 4; ++nt)
                    orow[nt * 16] = (f16)acc[mt][nt][reg];
            }
        }
    }
}

// Layer-5 GEMM: t5(f16) = h4[NN,64](f16) @ W5[64,16](f32).
// One thread per row: vector h8 loads (no redundant row reads), 16 outputs.
__global__ __launch_bounds__(256) void gemm5_kernel(const f16* __restrict__ h4,
                                                    const float* __restrict__ W5,
                                                    f16* __restrict__ t5, int nNodes) {
    int i = blockIdx.x * 256 + threadIdx.x;
    if (i >= nNodes) return;
    const h8* a = (const h8*)(h4 + (size_t)i * 64);
    float s[16];
#pragma unroll
    for (int j = 0; j < 16; ++j) s[j] = 0.f;
#pragma unroll
    for (int kb = 0; kb < 8; ++kb) {
        h8 av = a[kb];
#pragma unroll
        for (int t = 0; t < 8; ++t) {
            float aval = (float)av[t];
            const float* wrow = W5 + (kb * 8 + t) * 16;
#pragma unroll
            for (int j = 0; j < 16; ++j) s[j] += aval * wrow[j];
        }
    }
    Pack8 o0, o1;
#pragma unroll
    for (int j = 0; j < 8; ++j) { o0.h[j] = (f16)s[j]; o1.h[j] = (f16)s[j + 8]; }
    uint4* op = (uint4*)(t5 + (size_t)i * 16);
    op[0] = o0.v;
    op[1] = o1.v;
}

// Pool + classifier
__global__ __launch_bounds__(256) void pool_kernel(const float* __restrict__ h5,
                                                   float* __restrict__ pool) {
    __shared__ float red[256];
    int c = blockIdx.x;
    float s = 0.f;
    for (int i = threadIdx.x; i < NN; i += 256) s += h5[(size_t)i * 16 + c];
    red[threadIdx.x] = s;
    __syncthreads();
    for (int off = 128; off > 0; off >>= 1) {
        if ((int)threadIdx.x < off) red[threadIdx.x] += red[threadIdx.x + off];
        __syncthreads();
    }
    if (threadIdx.x == 0) pool[c] = red[0];
}

__global__ void final_kernel(const float* __restrict__ pool, const float* __restrict__ Wl,
                             const float* __restrict__ bl, float* __restrict__ out) {
    int j = threadIdx.x;
    if (j < 3) {
        float s = 0.f;
#pragma unroll
        for (int c = 0; c < 16; ++c) s += pool[c] * Wl[c * 3 + j];
        out[j] = s * (1.0f / (float)NN) + bl[j];
    }
}

// ---------------------------------------------------------------------------
// Host launcher — workspace ledger ~205 MB (+32 KB w4t).
// ---------------------------------------------------------------------------
extern "C" void kernel_launch(void* const* d_in, const int* in_sizes, int n_in,
                              void* d_out, int out_size, void* d_ws, size_t ws_size,
                              hipStream_t stream) {
    (void)in_sizes; (void)n_in; (void)out_size; (void)ws_size;

    const float* x  = (const float*)d_in[0];
    const int*   ei = (const int*)d_in[1];
    const float* W1 = (const float*)d_in[2];
    const float* b1 = (const float*)d_in[3];
    const float* W2 = (const float*)d_in[4];
    const float* b2 = (const float*)d_in[5];
    const float* W3 = (const float*)d_in[6];
    const float* b3 = (const float*)d_in[7];
    const float* W4 = (const float*)d_in[8];
    const float* b4 = (const float*)d_in[9];
    const float* W5 = (const float*)d_in[10];
    const float* b5 = (const float*)d_in[11];
    const float* Wl = (const float*)d_in[12];
    const float* bl = (const float*)d_in[13];
    float* out = (float*)d_out;

    const int* srcp = ei;
    const int* dstp = ei + NE;

    char* p = (char*)d_ws;
    auto carve = [&](size_t bytes) {
        char* r = p;
        p += (bytes + 255) & ~(size_t)255;
        return r;
    };
    int*   deg  = (int*)carve(NN * 4);
    int*   cur  = (int*)carve(NN * 4);
    int*   rs   = (int*)carve((NN + 1) * 4);
    int*   bsum = (int*)carve(256 * 4);
    int*   csr  = (int*)carve((size_t)NE * 4);
    float* dinv = (float*)carve(NN * 4);
    float* aggx = (float*)carve((size_t)NN * 3 * 4);
    float* pool = (float*)carve(16 * 4);
    float* w1p  = (float*)carve((size_t)4096 * 4 * 4);       // 64 KB
    f16*   w2t  = (f16*)carve((size_t)1024 * 4096 * 2);      // 8.4 MB
    f16*   w3t  = (f16*)carve((size_t)256 * 1024 * 2);       // 0.5 MB
    f16*   w4t  = (f16*)carve((size_t)64 * 256 * 2);         // 32 KB
    unsigned char* tbuf = (unsigned char*)carve((size_t)NN * 1024);  // 51.2 MB: fp8 t2/t3, f16 t4/t5 view
    f16*   h2   = (f16*)carve((size_t)NN * 1024 * 2);        // 102.4 MB
    f16*   h3   = (f16*)carve((size_t)NN * 256 * 2);         // 25.6 MB
    f16*   h4   = (f16*)carve((size_t)NN * 64 * 2);          // 6.4 MB
    float* h5   = (float*)carve((size_t)NN * 16 * 4);        // 3.2 MB
    f16*   tf16 = (f16*)tbuf;                                // f16 view for t4/t5

    const int NB = (NN + 255) / 256;  // 196

    zero_int_kernel<<<NB, 256, 0, stream>>>(deg, NN);
    zero_int_kernel<<<NB, 256, 0, stream>>>(cur, NN);
    count_kernel<<<(NE + 255) / 256, 256, 0, stream>>>(dstp, deg, NE);
    dinv_kernel<<<NB, 256, 0, stream>>>(deg, dinv, NN);
    scan1_kernel<<<NB, 256, 0, stream>>>(deg, rs, bsum, NN);
    scan2_kernel<<<1, 256, 0, stream>>>(bsum, rs, NB, NN);
    scan3_kernel<<<NB, 256, 0, stream>>>(rs, bsum, NN);
    fill_kernel<<<(NE + 255) / 256, 256, 0, stream>>>(srcp, dstp, rs, cur, csr, NE);

    // Weight prep
    pack_w1_kernel<<<16, 256, 0, stream>>>(W1, b1, w1p);
    tconv_kernel<<<dim3(1024 / 32, 4096 / 32), 256, 0, stream>>>(W2, w2t, 4096, 1024);
    tconv_kernel<<<dim3(256 / 32, 1024 / 32), 256, 0, stream>>>(W3, w3t, 1024, 256);
    tconv_kernel<<<dim3(64 / 32, 256 / 32), 256, 0, stream>>>(W4, w4t, 256, 64);

    // aggx = A_hat @ x (width 3, fp32) — TPN=3: 3 lanes/node for occupancy
    agg_kernel<3, 3, false, false, float, float><<<(NN + 84) / 85, 256, 0, stream>>>(
        x, dinv, rs, csr, nullptr, aggx, 3, NN);

    const int MB2 = (NN + 127) / 128;  // 391

    // Layers 1+2 fused: one 512-thread MFMA launch for all 1024 cols (fp8 out)
    gemm12_mfma10<<<dim3(MB2, 4), 512, 0, stream>>>(aggx, w1p, w2t, tbuf);
    // h2 = relu(A_hat t2 + b2): ONE pass, uint4/lane (16 B) per edge
    agg_fp8_1024<true><<<(NN + 3) / 4, 256, 0, stream>>>(
        tbuf, dinv, rs, csr, b2, h2, NN);

    // Layer 3 (MFMA, fp8 out): t3 = h2 @ W3; h3 = relu(A_hat t3 + b3)
    gemm_mfma<<<dim3(2, MB2), 256, 0, stream>>>(
        h2, 1024, w3t, 1024, tbuf, 256, NN);
    agg_fp8_256<true><<<(NN + 3) / 4, 256, 0, stream>>>(
        tbuf, 256, dinv, rs, csr, b3, h3, 256, NN);

    // Layer 4 (MFMA, f16 out): t4 = h3 @ W4; h4 = relu(A_hat t4 + b4) -> f16
    gemm_mfma_n64<<<MB2, 256, 0, stream>>>(h3, w4t, tf16, NN);
    agg_kernel<64, 64, true, true, f16, f16><<<(NN + 3) / 4, 256, 0, stream>>>(
        tf16, dinv, rs, csr, b4, h4, 64, NN);

    // Layer 5: t5(f16) = h4 @ W5 [NN,16]; h5 = A_hat t5 + b5 (no relu, f32)
    gemm5_kernel<<<(NN + 255) / 256, 256, 0, stream>>>(h4, W5, tf16, NN);
    agg_kernel<16, 16, false, true, f16, float><<<(NN + 15) / 16, 256, 0, stream>>>(
        tf16, dinv, rs, csr, b5, h5, 16, NN);

    // Global mean pool + classifier
    pool_kernel<<<16, 256, 0, stream>>>(h5, pool);
    final_kernel<<<1, 64, 0, stream>>>(pool, Wl, bl, out);
}

// Round 15
// 1476.363 us; speedup vs baseline: 1.2321x; 1.0572x over previous
//
#include <hip/hip_runtime.h>
#include <stdint.h>

#define NN 50000
#define NE 1600000

typedef _Float16 f16;
typedef __attribute__((ext_vector_type(8))) _Float16 h8;
typedef __attribute__((ext_vector_type(4))) _Float16 h4v;
typedef __attribute__((ext_vector_type(4))) float f32x4;
typedef __attribute__((ext_vector_type(2))) float f32x2;

union PackU { unsigned int u; f16 h[2]; };
union Pack4 { uint2 v; f16 h[4]; };
union Pack8 { uint4 v; f16 h[8]; };
union U64c  { uint2 u; long long l; };

__device__ __forceinline__ void storev(float* p, float v) { *p = v; }
__device__ __forceinline__ void storev(f16* p, float v) { *p = (f16)v; }

__device__ __forceinline__ unsigned char f2fp8(float v) {
    int pk = __builtin_amdgcn_cvt_pk_fp8_f32(v, v, 0, false);
    return (unsigned char)(pk & 0xff);
}

// ---------------------------------------------------------------------------
// Preprocessing
// ---------------------------------------------------------------------------
__global__ __launch_bounds__(256) void zero_int_kernel(int* __restrict__ p, int n) {
    int i = blockIdx.x * 256 + threadIdx.x;
    if (i < n) p[i] = 0;
}

__global__ __launch_bounds__(256) void count_kernel(const int* __restrict__ dst,
                                                    int* __restrict__ deg, int nE) {
    int e = blockIdx.x * 256 + threadIdx.x;
    if (e < nE) atomicAdd(&deg[dst[e]], 1);
}

__global__ __launch_bounds__(256) void dinv_kernel(const int* __restrict__ deg,
                                                   float* __restrict__ dinv, int n) {
    int i = blockIdx.x * 256 + threadIdx.x;
    if (i < n) dinv[i] = rsqrtf((float)deg[i] + 1.0f);
}

// Parallel 3-phase exclusive scan over 50000 ints (196 blocks of 256).
__global__ __launch_bounds__(256) void scan1_kernel(const int* __restrict__ cnt,
                                                    int* __restrict__ rs,
                                                    int* __restrict__ bsum, int n) {
    __shared__ int sm[256];
    int b = blockIdx.x, t = threadIdx.x, i = b * 256 + t;
    int v = (i < n) ? cnt[i] : 0;
    sm[t] = v;
    __syncthreads();
    for (int off = 1; off < 256; off <<= 1) {
        int x = 0;
        if (t >= off) x = sm[t - off];
        __syncthreads();
        if (t >= off) sm[t] += x;
        __syncthreads();
    }
    if (i < n) rs[i] = sm[t] - v;  // block-local exclusive
    if (t == 255) bsum[b] = sm[255];
}

__global__ __launch_bounds__(256) void scan2_kernel(int* __restrict__ bsum,
                                                    int* __restrict__ rs, int nb, int n) {
    __shared__ int sm[256];
    int t = threadIdx.x;
    int v = (t < nb) ? bsum[t] : 0;
    sm[t] = v;
    __syncthreads();
    for (int off = 1; off < 256; off <<= 1) {
        int x = 0;
        if (t >= off) x = sm[t - off];
        __syncthreads();
        if (t >= off) sm[t] += x;
        __syncthreads();
    }
    if (t < nb) bsum[t] = sm[t] - v;  // exclusive block offsets
    if (t == 255) rs[n] = sm[255];    // grand total (= nE)
}

__global__ __launch_bounds__(256) void scan3_kernel(int* __restrict__ rs,
                                                    const int* __restrict__ bsum, int n) {
    int i = blockIdx.x * 256 + threadIdx.x;
    if (i < n) rs[i] += bsum[blockIdx.x];
}

__global__ __launch_bounds__(256) void fill_kernel(const int* __restrict__ src,
                                                   const int* __restrict__ dst,
                                                   const int* __restrict__ rs,
                                                   int* __restrict__ cur,
                                                   int* __restrict__ csr, int nE) {
    int e = blockIdx.x * 256 + threadIdx.x;
    if (e < nE) {
        int d = dst[e];
        int p = rs[d] + atomicAdd(&cur[d], 1);
        csr[p] = src[e];
    }
}

// w1p[k*4 + {0,1,2,3}] = {W1[0][k], W1[1][k], W1[2][k], b1[k]}
__global__ __launch_bounds__(256) void pack_w1_kernel(const float* __restrict__ W1,
                                                      const float* __restrict__ b1,
                                                      float* __restrict__ w1p) {
    int k = blockIdx.x * 256 + threadIdx.x;
    if (k < 4096) {
        w1p[k * 4 + 0] = W1[k];
        w1p[k * 4 + 1] = W1[4096 + k];
        w1p[k * 4 + 2] = W1[8192 + k];
        w1p[k * 4 + 3] = b1[k];
    }
}

// Transpose-convert: Wt[n][k] = f16(W[k][n]); K, N multiples of 32.
__global__ __launch_bounds__(256) void tconv_kernel(const float* __restrict__ W,
                                                    f16* __restrict__ Wt,
                                                    int K, int N) {
    __shared__ float tile[32][33];
    int kb = blockIdx.y * 32, nb = blockIdx.x * 32;
    int tx = threadIdx.x & 31, ty = threadIdx.x >> 5;
    for (int r = ty; r < 32; r += 8)
        tile[r][tx] = W[(size_t)(kb + r) * N + nb + tx];
    __syncthreads();
    for (int r = ty; r < 32; r += 8)
        Wt[(size_t)(nb + r) * K + kb + tx] = (f16)tile[tx][r];
}

// Transpose-convert to fp8 with SCALE: Wt[n][k] = fp8(scale * W[k][n]).
// W2 std = 1/64 = e4m3's min NORMAL (2^-6): ~half the weights would quantize
// as subnormals (>=10% rel err) — the r14 accuracy failure. scale=64 moves
// std to 1.0 (full mantissa, 4-sigma = 4 << 448 no saturation); gemm12's
// epilogue descales by 1/64 so t2 and all downstream kernels are unchanged.
__global__ __launch_bounds__(256) void tconv_fp8_kernel(const float* __restrict__ W,
                                                        unsigned char* __restrict__ Wt,
                                                        int K, int N, float scale) {
    __shared__ float tile[32][33];
    int kb = blockIdx.y * 32, nb = blockIdx.x * 32;
    int tx = threadIdx.x & 31, ty = threadIdx.x >> 5;
    for (int r = ty; r < 32; r += 8)
        tile[r][tx] = W[(size_t)(kb + r) * N + nb + tx];
    __syncthreads();
    for (int r = ty; r < 32; r += 8)
        Wt[(size_t)(nb + r) * K + kb + tx] = f2fp8(tile[tx][r] * scale);
}

// ---------------------------------------------------------------------------
// Input-typed aggregation (widths 3, 64, 16). InT = float or f16.
// ---------------------------------------------------------------------------
template <int F, int TPN, bool RELU, bool BIAS, typename InT, typename OutT>
__global__ __launch_bounds__(256) void agg_kernel(const InT* __restrict__ t,
                                                  const float* __restrict__ dinv,
                                                  const int* __restrict__ rs,
                                                  const int* __restrict__ csr,
                                                  const float* __restrict__ bias,
                                                  OutT* __restrict__ out, int out_ld,
                                                  int nNodes) {
    constexpr int NPB = 256 / TPN;
    constexpr int C   = F / TPN;
    static_assert(TPN * C == F, "F must be TPN*C");
    if ((int)threadIdx.x >= NPB * TPN) return;  // tail guard for TPN=3
    int node = blockIdx.x * NPB + (int)threadIdx.x / TPN;
    if (node >= nNodes) return;
    int lane = (int)threadIdx.x % TPN;

    float acc[C];
#pragma unroll
    for (int c = 0; c < C; ++c) acc[c] = 0.f;

    int e0 = rs[node], e1 = rs[node + 1];
    for (int e = e0; e < e1; ++e) {
        int s = csr[e];
        float w = dinv[s];
        const InT* tr = t + (size_t)s * F;
#pragma unroll
        for (int c = 0; c < C; ++c) acc[c] += w * (float)tr[lane + c * TPN];
    }
    float di = dinv[node];
    const InT* ti = t + (size_t)node * F;
    OutT* oi = out + (size_t)node * out_ld;
#pragma unroll
    for (int c = 0; c < C; ++c) {
        int col = lane + c * TPN;
        float v = di * acc[c] + di * di * (float)ti[col];
        if (BIAS) v += bias[col];
        if (RELU) v = fmaxf(v, 0.f);
        storev(oi + col, v);
    }
}

// ---------------------------------------------------------------------------
// fp8 aggregation, F=1024, SINGLE PASS: 64 lanes/node (4 nodes/block), each
// lane loads a uint4 (16 B = 16 fp8 cols) per edge.
// ---------------------------------------------------------------------------
template <bool RELU>
__global__ __launch_bounds__(256) void agg_fp8_1024(const unsigned char* __restrict__ t,
                                                    const float* __restrict__ dinv,
                                                    const int* __restrict__ rs,
                                                    const int* __restrict__ csr,
                                                    const float* __restrict__ bias,
                                                    f16* __restrict__ out, int nNodes) {
    int node = blockIdx.x * 4 + ((int)threadIdx.x >> 6);
    if (node >= nNodes) return;
    int lane = (int)threadIdx.x & 63;

    float acc[16];
#pragma unroll
    for (int j = 0; j < 16; ++j) acc[j] = 0.f;

    int e0 = rs[node], e1 = rs[node + 1];
    int e = e0;
    for (; e + 1 < e1; e += 2) {
        int s0 = csr[e], s1 = csr[e + 1];
        float w0 = dinv[s0], w1 = dinv[s1];
        uint4 u0 = ((const uint4*)(t + (size_t)s0 * 1024))[lane];
        uint4 u1 = ((const uint4*)(t + (size_t)s1 * 1024))[lane];
        const unsigned int uw0[4] = {u0.x, u0.y, u0.z, u0.w};
        const unsigned int uw1[4] = {u1.x, u1.y, u1.z, u1.w};
#pragma unroll
        for (int q = 0; q < 4; ++q) {
            f32x2 l0 = __builtin_amdgcn_cvt_pk_f32_fp8((int)uw0[q], false);
            f32x2 h0 = __builtin_amdgcn_cvt_pk_f32_fp8((int)uw0[q], true);
            f32x2 l1 = __builtin_amdgcn_cvt_pk_f32_fp8((int)uw1[q], false);
            f32x2 h1 = __builtin_amdgcn_cvt_pk_f32_fp8((int)uw1[q], true);
            acc[q * 4 + 0] += w0 * l0.x + w1 * l1.x;
            acc[q * 4 + 1] += w0 * l0.y + w1 * l1.y;
            acc[q * 4 + 2] += w0 * h0.x + w1 * h1.x;
            acc[q * 4 + 3] += w0 * h0.y + w1 * h1.y;
        }
    }
    if (e < e1) {
        int s0 = csr[e];
        float w0 = dinv[s0];
        uint4 u0 = ((const uint4*)(t + (size_t)s0 * 1024))[lane];
        const unsigned int uw0[4] = {u0.x, u0.y, u0.z, u0.w};
#pragma unroll
        for (int q = 0; q < 4; ++q) {
            f32x2 l0 = __builtin_amdgcn_cvt_pk_f32_fp8((int)uw0[q], false);
            f32x2 h0 = __builtin_amdgcn_cvt_pk_f32_fp8((int)uw0[q], true);
            acc[q * 4 + 0] += w0 * l0.x;
            acc[q * 4 + 1] += w0 * l0.y;
            acc[q * 4 + 2] += w0 * h0.x;
            acc[q * 4 + 3] += w0 * h0.y;
        }
    }
    float di = dinv[node], di2 = di * di;
    uint4 us = ((const uint4*)(t + (size_t)node * 1024))[lane];
    const unsigned int uws[4] = {us.x, us.y, us.z, us.w};
    Pack8 o0, o1;
#pragma unroll
    for (int q = 0; q < 4; ++q) {
        f32x2 sl = __builtin_amdgcn_cvt_pk_f32_fp8((int)uws[q], false);
        f32x2 sh = __builtin_amdgcn_cvt_pk_f32_fp8((int)uws[q], true);
        float4 b = *(const float4*)(bias + 16 * lane + q * 4);
        float v0 = di * acc[q * 4 + 0] + di2 * sl.x + b.x;
        float v1 = di * acc[q * 4 + 1] + di2 * sl.y + b.y;
        float v2 = di * acc[q * 4 + 2] + di2 * sh.x + b.z;
        float v3 = di * acc[q * 4 + 3] + di2 * sh.y + b.w;
        if (RELU) {
            v0 = fmaxf(v0, 0.f); v1 = fmaxf(v1, 0.f);
            v2 = fmaxf(v2, 0.f); v3 = fmaxf(v3, 0.f);
        }
        Pack8& dst8 = (q < 2) ? o0 : o1;
        int base = (q & 1) * 4;
        dst8.h[base + 0] = (f16)v0;
        dst8.h[base + 1] = (f16)v1;
        dst8.h[base + 2] = (f16)v2;
        dst8.h[base + 3] = (f16)v3;
    }
    uint4* orow = (uint4*)(out + (size_t)node * 1024 + 16 * lane);
    orow[0] = o0.v;
    orow[1] = o1.v;
}

// ---------------------------------------------------------------------------
// fp8 aggregation over a 256-col tensor (layer 3): 64 lanes/node, one uint
// (4 fp8 cols) per lane per edge. Round-8-proven structure.
// ---------------------------------------------------------------------------
template <bool RELU>
__global__ __launch_bounds__(256) void agg_fp8_256(const unsigned char* __restrict__ t,
                                                   int in_ld,
                                                   const float* __restrict__ dinv,
                                                   const int* __restrict__ rs,
                                                   const int* __restrict__ csr,
                                                   const float* __restrict__ bias,
                                                   f16* __restrict__ out,
                                                   int out_ld, int nNodes) {
    int node = blockIdx.x * 4 + ((int)threadIdx.x >> 6);
    if (node >= nNodes) return;
    int lane = (int)threadIdx.x & 63;

    float acc0 = 0.f, acc1 = 0.f, acc2 = 0.f, acc3 = 0.f;
    int e0 = rs[node], e1 = rs[node + 1];
    int e = e0;
    for (; e + 1 < e1; e += 2) {
        int s0 = csr[e], s1 = csr[e + 1];
        float w0 = dinv[s0], w1 = dinv[s1];
        unsigned int u0 = ((const unsigned int*)(t + (size_t)s0 * in_ld))[lane];
        unsigned int u1 = ((const unsigned int*)(t + (size_t)s1 * in_ld))[lane];
        f32x2 l0 = __builtin_amdgcn_cvt_pk_f32_fp8((int)u0, false);
        f32x2 h0 = __builtin_amdgcn_cvt_pk_f32_fp8((int)u0, true);
        f32x2 l1 = __builtin_amdgcn_cvt_pk_f32_fp8((int)u1, false);
        f32x2 h1 = __builtin_amdgcn_cvt_pk_f32_fp8((int)u1, true);
        acc0 += w0 * l0.x + w1 * l1.x;
        acc1 += w0 * l0.y + w1 * l1.y;
        acc2 += w0 * h0.x + w1 * h1.x;
        acc3 += w0 * h0.y + w1 * h1.y;
    }
    if (e < e1) {
        int s0 = csr[e];
        float w0 = dinv[s0];
        unsigned int u0 = ((const unsigned int*)(t + (size_t)s0 * in_ld))[lane];
        f32x2 l0 = __builtin_amdgcn_cvt_pk_f32_fp8((int)u0, false);
        f32x2 h0 = __builtin_amdgcn_cvt_pk_f32_fp8((int)u0, true);
        acc0 += w0 * l0.x;
        acc1 += w0 * l0.y;
        acc2 += w0 * h0.x;
        acc3 += w0 * h0.y;
    }
    float di = dinv[node], di2 = di * di;
    unsigned int us = ((const unsigned int*)(t + (size_t)node * in_ld))[lane];
    f32x2 sl = __builtin_amdgcn_cvt_pk_f32_fp8((int)us, false);
    f32x2 sh = __builtin_amdgcn_cvt_pk_f32_fp8((int)us, true);
    float4 b = *(const float4*)(bias + 4 * lane);
    float v0 = di * acc0 + di2 * sl.x + b.x;
    float v1 = di * acc1 + di2 * sl.y + b.y;
    float v2 = di * acc2 + di2 * sh.x + b.z;
    float v3 = di * acc3 + di2 * sh.y + b.w;
    if (RELU) {
        v0 = fmaxf(v0, 0.f); v1 = fmaxf(v1, 0.f);
        v2 = fmaxf(v2, 0.f); v3 = fmaxf(v3, 0.f);
    }
    Pack4 pk;
    pk.h[0] = (f16)v0; pk.h[1] = (f16)v1; pk.h[2] = (f16)v2; pk.h[3] = (f16)v3;
    *(uint2*)(out + (size_t)node * out_ld + 4 * lane) = pk.v;
}

// ---------------------------------------------------------------------------
// MFMA GEMM kernels. f16 kernels: LDS row stride 40 f16 = 80 B.
// Fragments: A[m=lane&15][k=(lane>>4)*8+j]; B^T rows; C/D col=lane&15,
// row=(lane>>4)*4+reg (dtype-independent on gfx950).
// ---------------------------------------------------------------------------
#define LDSTR 40
#define BSTR 40  // fp8 LDS row stride in BYTES (32 data + 8 pad)

// Fused layer1+2, round-28 (mfma14 = mfma13 + W2 scale fix): mfma10's EXACT
// schedule with fp8 e4m3 operands via mfma_f32_16x16x32_fp8_fp8.
//  * r14 failed numerics (7.32e-4 vs 6.79e-4) because W2 std = 2^-6 =
//    e4m3's min normal -> ~half the weights were SUBNORMAL (>=10% rel err).
//  * Fix: W2 stored as fp8(64*W2) (std -> 1.0, full mantissa; no
//    saturation); epilogue descales acc * 1/64 before f2fp8. t2 keeps its
//    original scale -> all downstream kernels byte-identical to r13-passing.
//  * Staging halves on gemm12's proven binding resource (LDS pipe + issue
//    stream): B 32->16 B/thread, A 8->4 B/thread, frag reads b128->b64,
//    LDS 61.4 -> 30.7 KB.
// Pre-committed: failed check or dur >= 740 -> restore r13 f16 kernel.
__global__ __launch_bounds__(512, 4) void gemm12_mfma14(const float* __restrict__ aggx,
                                                        const float* __restrict__ w1p,
                                                        const unsigned char* __restrict__ Bt8,
                                                        unsigned char* __restrict__ t2) {
    __shared__ unsigned char As[2 * 128 * BSTR] __attribute__((aligned(16)));  // 10.2 KB
    __shared__ unsigned char Bs[2 * 256 * BSTR] __attribute__((aligned(16)));  // 20.5 KB
    int tid = threadIdx.x;
    int m0  = blockIdx.x * 128;
    int n0c = blockIdx.y * 256;  // column chunk base in W2

    // A-recompute: 2 m-rows x 4 k per thread (64 row-pairs x 8 k-groups)
    int mg = tid >> 3;   // 0..63 -> rows 2mg, 2mg+1
    int kg = tid & 7;    // k group: kg*4 .. kg*4+3
    float a0[2], a1[2], a2[2];
#pragma unroll
    for (int j = 0; j < 2; ++j) {
        int gm = m0 + mg * 2 + j;
        if (gm < NN) {
            a0[j] = aggx[gm * 3 + 0];
            a1[j] = aggx[gm * 3 + 1];
            a2[j] = aggx[gm * 3 + 2];
        } else {
            a0[j] = a1[j] = a2[j] = 0.f;
        }
    }

    // B staging: 2 threads per n-row, 16 fp8 (16 B) each
    int brow = tid >> 1;            // 0..255
    int bkof = (tid & 1) * 16;
    const unsigned char* bbase = Bt8 + (size_t)(n0c + brow) * 4096 + bkof;

    int lane   = tid & 63;
    int wv     = tid >> 6;          // 0..7
    int wm     = (wv >> 2) * 64;    // 0 or 64
    int wn     = (wv & 3) * 64;     // 0,64,128,192
    int fr_m   = lane & 15;
    int kb8    = (lane >> 4) * 8;   // fragment k-chunk offset in BYTES

    // A-stage helper: h1 f32 -> fp8 x4 -> one dword per row
    auto stageA = [&](unsigned char* dstAs, int kk) {
        int kb = kk + kg * 4;
        float4 wk0 = *(const float4*)(w1p + (size_t)(kb + 0) * 4);
        float4 wk1 = *(const float4*)(w1p + (size_t)(kb + 1) * 4);
        float4 wk2 = *(const float4*)(w1p + (size_t)(kb + 2) * 4);
        float4 wk3 = *(const float4*)(w1p + (size_t)(kb + 3) * 4);
#pragma unroll
        for (int j = 0; j < 2; ++j) {
            float h0 = fmaxf(a0[j] * wk0.x + a1[j] * wk0.y + a2[j] * wk0.z + wk0.w, 0.f);
            float h1 = fmaxf(a0[j] * wk1.x + a1[j] * wk1.y + a2[j] * wk1.z + wk1.w, 0.f);
            float h2 = fmaxf(a0[j] * wk2.x + a1[j] * wk2.y + a2[j] * wk2.z + wk2.w, 0.f);
            float h3 = fmaxf(a0[j] * wk3.x + a1[j] * wk3.y + a2[j] * wk3.z + wk3.w, 0.f);
            int pk = __builtin_amdgcn_cvt_pk_fp8_f32(h0, h1, 0, false);
            pk = __builtin_amdgcn_cvt_pk_fp8_f32(h2, h3, pk, true);
            *(unsigned int*)(&dstAs[(mg * 2 + j) * BSTR + kg * 4]) = (unsigned int)pk;
        }
    };

    // ---- prologue: stage buffer 0 with k=0; load B regs for k=32 ----
    uint4 pb = *(const uint4*)(bbase);
    stageA(As, 0);
    *(uint2*)(&Bs[brow * BSTR + bkof])     = make_uint2(pb.x, pb.y);
    *(uint2*)(&Bs[brow * BSTR + bkof + 8]) = make_uint2(pb.z, pb.w);
    pb = *(const uint4*)(bbase + 32);

    f32x4 acc[4][4];
#pragma unroll
    for (int i = 0; i < 4; ++i)
#pragma unroll
        for (int j = 0; j < 4; ++j) acc[i][j] = (f32x4){0.f, 0.f, 0.f, 0.f};

    int p = 0;
    for (int k0 = 0; k0 < 4096; k0 += 32) {
        __syncthreads();  // buf[p] fully staged; all reads of buf[p^1] done
        const unsigned char* Asc = As + p * (128 * BSTR);
        const unsigned char* Bsc = Bs + p * (256 * BSTR);
        unsigned char* Asn = As + (p ^ 1) * (128 * BSTR);
        unsigned char* Bsn = Bs + (p ^ 1) * (256 * BSTR);

        // ---- stage NEXT K-tile into buf[p^1] (overlaps other waves' MFMA) ----
        int k1 = k0 + 32;
        if (k1 < 4096) {
            *(uint2*)(&Bsn[brow * BSTR + bkof])     = make_uint2(pb.x, pb.y);
            *(uint2*)(&Bsn[brow * BSTR + bkof + 8]) = make_uint2(pb.z, pb.w);
            stageA(Asn, k1);
        }

        // ---- frag reads from current buffer (b64) ----
        U64c af[4];
#pragma unroll
        for (int mt = 0; mt < 4; ++mt)
            af[mt].u = *(const uint2*)(&Asc[(wm + mt * 16 + fr_m) * BSTR + kb8]);

        // ---- prefetch B for k+64 (drains under MFMA phase) ----
        int k2 = k0 + 64;
        if (k2 < 4096) {
            pb = *(const uint4*)(bbase + k2);
        }

#pragma unroll
        for (int nt = 0; nt < 4; ++nt) {
            U64c bf;
            bf.u = *(const uint2*)(&Bsc[(wn + nt * 16 + fr_m) * BSTR + kb8]);
#pragma unroll
            for (int mt = 0; mt < 4; ++mt)
                acc[mt][nt] = __builtin_amdgcn_mfma_f32_16x16x32_fp8_fp8(
                    af[mt].l, bf.l, acc[mt][nt], 0, 0, 0);
        }
        p ^= 1;
    }

    // Epilogue: descale by 1/64 (undo the W2 fp8 range scaling), then fp8.
    const float DS = 0.015625f;
#pragma unroll
    for (int mt = 0; mt < 4; ++mt) {
#pragma unroll
        for (int reg = 0; reg < 4; ++reg) {
            int gm = m0 + wm + mt * 16 + (lane >> 4) * 4 + reg;
            if (gm < NN) {
                unsigned char* orow = t2 + (size_t)gm * 1024 + n0c + wn + fr_m;
#pragma unroll
                for (int nt = 0; nt < 4; ++nt)
                    orow[nt * 16] = f2fp8(acc[mt][nt][reg] * DS);
            }
        }
    }
}

// Generic MFMA GEMM (layer 3): C(fp8)[M,ldc] = A[M,lda](f16) @ Bt[N][K](f16)^T
// 128x128 tile, register-prefetched staging. 20.5 KB LDS -> 8 blocks/CU.
__global__ __launch_bounds__(256) void gemm_mfma(const f16* __restrict__ A, int lda,
                                                 const f16* __restrict__ Bt, int K,
                                                 unsigned char* __restrict__ C, int ldc,
                                                 int M) {
    __shared__ f16 As[128 * LDSTR] __attribute__((aligned(16)));
    __shared__ f16 Bs[128 * LDSTR] __attribute__((aligned(16)));
    int tid = threadIdx.x;
    int m0 = blockIdx.y * 128;
    int n0 = blockIdx.x * 128;

    int row = tid >> 1;
    int kof = (tid & 1) * 16;
    int am  = m0 + row;
    if (am > M - 1) am = M - 1;

    int lane   = tid & 63;
    int wv     = tid >> 6;
    int fr_m   = lane & 15;
    int khalf8 = (lane >> 4) * 8;

    const f16* abase = A + (size_t)am * lda + kof;
    const f16* bbase = Bt + (size_t)(n0 + row) * K + kof;

    h8 pa0 = *(const h8*)(abase);
    h8 pa1 = *(const h8*)(abase + 8);
    h8 pb0 = *(const h8*)(bbase);
    h8 pb1 = *(const h8*)(bbase + 8);

    f32x4 acc[2][8];
#pragma unroll
    for (int i = 0; i < 2; ++i)
#pragma unroll
        for (int j = 0; j < 8; ++j) acc[i][j] = (f32x4){0.f, 0.f, 0.f, 0.f};

    for (int k0 = 0; k0 < K; k0 += 32) {
        *(h8*)(&As[row * LDSTR + kof]) = pa0;
        *(h8*)(&As[row * LDSTR + kof + 8]) = pa1;
        *(h8*)(&Bs[row * LDSTR + kof]) = pb0;
        *(h8*)(&Bs[row * LDSTR + kof + 8]) = pb1;
        __syncthreads();

        int kn = k0 + 32;
        if (kn < K) {
            pa0 = *(const h8*)(abase + kn);
            pa1 = *(const h8*)(abase + kn + 8);
            pb0 = *(const h8*)(bbase + kn);
            pb1 = *(const h8*)(bbase + kn + 8);
        }

        h8 af0 = *(const h8*)(&As[(wv * 32 + fr_m) * LDSTR + khalf8]);
        h8 af1 = *(const h8*)(&As[(wv * 32 + 16 + fr_m) * LDSTR + khalf8]);
#pragma unroll
        for (int nt = 0; nt < 8; ++nt) {
            h8 bf = *(const h8*)(&Bs[(nt * 16 + fr_m) * LDSTR + khalf8]);
            acc[0][nt] = __builtin_amdgcn_mfma_f32_16x16x32_f16(af0, bf, acc[0][nt], 0, 0, 0);
            acc[1][nt] = __builtin_amdgcn_mfma_f32_16x16x32_f16(af1, bf, acc[1][nt], 0, 0, 0);
        }
        __syncthreads();
    }

#pragma unroll
    for (int mt = 0; mt < 2; ++mt) {
#pragma unroll
        for (int reg = 0; reg < 4; ++reg) {
            int gm = m0 + wv * 32 + mt * 16 + (lane >> 4) * 4 + reg;
            if (gm < M) {
                unsigned char* orow = C + (size_t)gm * ldc + n0 + fr_m;
#pragma unroll
                for (int nt = 0; nt < 8; ++nt)
                    orow[nt * 16] = f2fp8(acc[mt][nt][reg]);
            }
        }
    }
}

// ---------------------------------------------------------------------------
// Layer-4 MFMA GEMM: C(f16)[M,64] = A[M,256](f16) @ Bt[64][256](f16)^T.
// 128m x 64n tile, 4 waves. Same fragment pattern as gemm_mfma.
// ---------------------------------------------------------------------------
__global__ __launch_bounds__(256) void gemm_mfma_n64(const f16* __restrict__ A,
                                                     const f16* __restrict__ Bt,
                                                     f16* __restrict__ C, int M) {
    __shared__ f16 As[128 * LDSTR] __attribute__((aligned(16)));
    __shared__ f16 Bs[64 * LDSTR] __attribute__((aligned(16)));
    int tid = threadIdx.x;
    int m0 = blockIdx.x * 128;

    int row = tid >> 1;             // 0..127
    int kof = (tid & 1) * 16;
    int am  = m0 + row;
    if (am > M - 1) am = M - 1;

    int lane   = tid & 63;
    int wv     = tid >> 6;          // 0..3
    int fr_m   = lane & 15;
    int khalf8 = (lane >> 4) * 8;

    const f16* abase = A + (size_t)am * 256 + kof;
    int brow = (tid & 127) >> 1;    // 0..63
    const f16* bbase = Bt + (size_t)brow * 256 + kof;
    bool doB = tid < 128;

    h8 pa0 = *(const h8*)(abase);
    h8 pa1 = *(const h8*)(abase + 8);
    h8 pb0, pb1;
    if (doB) {
        pb0 = *(const h8*)(bbase);
        pb1 = *(const h8*)(bbase + 8);
    }

    f32x4 acc[2][4];
#pragma unroll
    for (int i = 0; i < 2; ++i)
#pragma unroll
        for (int j = 0; j < 4; ++j) acc[i][j] = (f32x4){0.f, 0.f, 0.f, 0.f};

    for (int k0 = 0; k0 < 256; k0 += 32) {
        *(h8*)(&As[row * LDSTR + kof]) = pa0;
        *(h8*)(&As[row * LDSTR + kof + 8]) = pa1;
        if (doB) {
            *(h8*)(&Bs[brow * LDSTR + kof]) = pb0;
            *(h8*)(&Bs[brow * LDSTR + kof + 8]) = pb1;
        }
        __syncthreads();

        int kn = k0 + 32;
        if (kn < 256) {
            pa0 = *(const h8*)(abase + kn);
            pa1 = *(const h8*)(abase + kn + 8);
            if (doB) {
                pb0 = *(const h8*)(bbase + kn);
                pb1 = *(const h8*)(bbase + kn + 8);
            }
        }

        h8 af0 = *(const h8*)(&As[(wv * 32 + fr_m) * LDSTR + khalf8]);
        h8 af1 = *(const h8*)(&As[(wv * 32 + 16 + fr_m) * LDSTR + khalf8]);
#pragma unroll
        for (int nt = 0; nt < 4; ++nt) {
            h8 bf = *(const h8*)(&Bs[(nt * 16 + fr_m) * LDSTR + khalf8]);
            acc[0][nt] = __builtin_amdgcn_mfma_f32_16x16x32_f16(af0, bf, acc[0][nt], 0, 0, 0);
            acc[1][nt] = __builtin_amdgcn_mfma_f32_16x16x32_f16(af1, bf, acc[1][nt], 0, 0, 0);
        }
        __syncthreads();
    }

#pragma unroll
    for (int mt = 0; mt < 2; ++mt) {
#pragma unroll
        for (int reg = 0; reg < 4; ++reg) {
            int gm = m0 + wv * 32 + mt * 16 + (lane >> 4) * 4 + reg;
            if (gm < M) {
                f16* orow = C + (size_t)gm * 64 + fr_m;
#pragma unroll
                for (int nt = 0; nt < 4; ++nt)
                    orow[nt * 16] = (f16)acc[mt][nt][reg];
            }
        }
    }
}

// Layer-5 GEMM: t5(f16) = h4[NN,64](f16) @ W5[64,16](f32).
// One thread per row: vector h8 loads, 16 outputs.
__global__ __launch_bounds__(256) void gemm5_kernel(const f16* __restrict__ h4,
                                                    const float* __restrict__ W5,
                                                    f16* __restrict__ t5, int nNodes) {
    int i = blockIdx.x * 256 + threadIdx.x;
    if (i >= nNodes) return;
    const h8* a = (const h8*)(h4 + (size_t)i * 64);
    float s[16];
#pragma unroll
    for (int j = 0; j < 16; ++j) s[j] = 0.f;
#pragma unroll
    for (int kb = 0; kb < 8; ++kb) {
        h8 av = a[kb];
#pragma unroll
        for (int t = 0; t < 8; ++t) {
            float aval = (float)av[t];
            const float* wrow = W5 + (kb * 8 + t) * 16;
#pragma unroll
            for (int j = 0; j < 16; ++j) s[j] += aval * wrow[j];
        }
    }
    Pack8 o0, o1;
#pragma unroll
    for (int j = 0; j < 8; ++j) { o0.h[j] = (f16)s[j]; o1.h[j] = (f16)s[j + 8]; }
    uint4* op = (uint4*)(t5 + (size_t)i * 16);
    op[0] = o0.v;
    op[1] = o1.v;
}

// Pool + classifier
__global__ __launch_bounds__(256) void pool_kernel(const float* __restrict__ h5,
                                                   float* __restrict__ pool) {
    __shared__ float red[256];
    int c = blockIdx.x;
    float s = 0.f;
    for (int i = threadIdx.x; i < NN; i += 256) s += h5[(size_t)i * 16 + c];
    red[threadIdx.x] = s;
    __syncthreads();
    for (int off = 128; off > 0; off >>= 1) {
        if ((int)threadIdx.x < off) red[threadIdx.x] += red[threadIdx.x + off];
        __syncthreads();
    }
    if (threadIdx.x == 0) pool[c] = red[0];
}

__global__ void final_kernel(const float* __restrict__ pool, const float* __restrict__ Wl,
                             const float* __restrict__ bl, float* __restrict__ out) {
    int j = threadIdx.x;
    if (j < 3) {
        float s = 0.f;
#pragma unroll
        for (int c = 0; c < 16; ++c) s += pool[c] * Wl[c * 3 + j];
        out[j] = s * (1.0f / (float)NN) + bl[j];
    }
}

// ---------------------------------------------------------------------------
// Host launcher — workspace ledger ~201 MB (w2f8 4.2 MB replaces w2t 8.4 MB).
// ---------------------------------------------------------------------------
extern "C" void kernel_launch(void* const* d_in, const int* in_sizes, int n_in,
                              void* d_out, int out_size, void* d_ws, size_t ws_size,
                              hipStream_t stream) {
    (void)in_sizes; (void)n_in; (void)out_size; (void)ws_size;

    const float* x  = (const float*)d_in[0];
    const int*   ei = (const int*)d_in[1];
    const float* W1 = (const float*)d_in[2];
    const float* b1 = (const float*)d_in[3];
    const float* W2 = (const float*)d_in[4];
    const float* b2 = (const float*)d_in[5];
    const float* W3 = (const float*)d_in[6];
    const float* b3 = (const float*)d_in[7];
    const float* W4 = (const float*)d_in[8];
    const float* b4 = (const float*)d_in[9];
    const float* W5 = (const float*)d_in[10];
    const float* b5 = (const float*)d_in[11];
    const float* Wl = (const float*)d_in[12];
    const float* bl = (const float*)d_in[13];
    float* out = (float*)d_out;

    const int* srcp = ei;
    const int* dstp = ei + NE;

    char* p = (char*)d_ws;
    auto carve = [&](size_t bytes) {
        char* r = p;
        p += (bytes + 255) & ~(size_t)255;
        return r;
    };
    int*   deg  = (int*)carve(NN * 4);
    int*   cur  = (int*)carve(NN * 4);
    int*   rs   = (int*)carve((NN + 1) * 4);
    int*   bsum = (int*)carve(256 * 4);
    int*   csr  = (int*)carve((size_t)NE * 4);
    float* dinv = (float*)carve(NN * 4);
    float* aggx = (float*)carve((size_t)NN * 3 * 4);
    float* pool = (float*)carve(16 * 4);
    float* w1p  = (float*)carve((size_t)4096 * 4 * 4);       // 64 KB
    unsigned char* w2f8 = (unsigned char*)carve((size_t)1024 * 4096);  // 4.2 MB
    f16*   w3t  = (f16*)carve((size_t)256 * 1024 * 2);       // 0.5 MB
    f16*   w4t  = (f16*)carve((size_t)64 * 256 * 2);         // 32 KB
    unsigned char* tbuf = (unsigned char*)carve((size_t)NN * 1024);  // 51.2 MB: fp8 t2/t3, f16 t4/t5 view
    f16*   h2   = (f16*)carve((size_t)NN * 1024 * 2);        // 102.4 MB
    f16*   h3   = (f16*)carve((size_t)NN * 256 * 2);         // 25.6 MB
    f16*   h4   = (f16*)carve((size_t)NN * 64 * 2);          // 6.4 MB
    float* h5   = (float*)carve((size_t)NN * 16 * 4);        // 3.2 MB
    f16*   tf16 = (f16*)tbuf;                                // f16 view for t4/t5

    const int NB = (NN + 255) / 256;  // 196

    zero_int_kernel<<<NB, 256, 0, stream>>>(deg, NN);
    zero_int_kernel<<<NB, 256, 0, stream>>>(cur, NN);
    count_kernel<<<(NE + 255) / 256, 256, 0, stream>>>(dstp, deg, NE);
    dinv_kernel<<<NB, 256, 0, stream>>>(deg, dinv, NN);
    scan1_kernel<<<NB, 256, 0, stream>>>(deg, rs, bsum, NN);
    scan2_kernel<<<1, 256, 0, stream>>>(bsum, rs, NB, NN);
    scan3_kernel<<<NB, 256, 0, stream>>>(rs, bsum, NN);
    fill_kernel<<<(NE + 255) / 256, 256, 0, stream>>>(srcp, dstp, rs, cur, csr, NE);

    // Weight prep (W2 scaled x64 into fp8 normal range; descaled in epilogue)
    pack_w1_kernel<<<16, 256, 0, stream>>>(W1, b1, w1p);
    tconv_fp8_kernel<<<dim3(1024 / 32, 4096 / 32), 256, 0, stream>>>(W2, w2f8, 4096, 1024, 64.0f);
    tconv_kernel<<<dim3(256 / 32, 1024 / 32), 256, 0, stream>>>(W3, w3t, 1024, 256);
    tconv_kernel<<<dim3(64 / 32, 256 / 32), 256, 0, stream>>>(W4, w4t, 256, 64);

    // aggx = A_hat @ x (width 3, fp32) — TPN=3: 3 lanes/node for occupancy
    agg_kernel<3, 3, false, false, float, float><<<(NN + 84) / 85, 256, 0, stream>>>(
        x, dinv, rs, csr, nullptr, aggx, 3, NN);

    const int MB2 = (NN + 127) / 128;  // 391

    // Layers 1+2 fused: fp8 MFMA (fp8 A on-the-fly, fp8 scaled W2), fp8 out
    gemm12_mfma14<<<dim3(MB2, 4), 512, 0, stream>>>(aggx, w1p, w2f8, tbuf);
    // h2 = relu(A_hat t2 + b2): ONE pass, uint4/lane (16 B) per edge
    agg_fp8_1024<true><<<(NN + 3) / 4, 256, 0, stream>>>(
        tbuf, dinv, rs, csr, b2, h2, NN);

    // Layer 3 (MFMA, fp8 out): t3 = h2 @ W3; h3 = relu(A_hat t3 + b3)
    gemm_mfma<<<dim3(2, MB2), 256, 0, stream>>>(
        h2, 1024, w3t, 1024, tbuf, 256, NN);
    agg_fp8_256<true><<<(NN + 3) / 4, 256, 0, stream>>>(
        tbuf, 256, dinv, rs, csr, b3, h3, 256, NN);

    // Layer 4 (MFMA, f16 out): t4 = h3 @ W4; h4 = relu(A_hat t4 + b4) -> f16
    gemm_mfma_n64<<<MB2, 256, 0, stream>>>(h3, w4t, tf16, NN);
    agg_kernel<64, 64, true, true, f16, f16><<<(NN + 3) / 4, 256, 0, stream>>>(
        tf16, dinv, rs, csr, b4, h4, 64, NN);

    // Layer 5: t5(f16) = h4 @ W5 [NN,16]; h5 = A_hat t5 + b5 (no relu, f32)
    gemm5_kernel<<<(NN + 255) / 256, 256, 0, stream>>>(h4, W5, tf16, NN);
    agg_kernel<16, 16, false, true, f16, float><<<(NN + 15) / 16, 256, 0, stream>>>(
        tf16, dinv, rs, csr, b5, h5, 16, NN);

    // Global mean pool + classifier
    pool_kernel<<<16, 256, 0, stream>>>(h5, pool);
    final_kernel<<<1, 64, 0, stream>>>(pool, Wl, bl, out);
}